// Round 16
// baseline (526.398 us; speedup 1.0000x reference)
//
#include <hip/hip_runtime.h>
#include <math.h>

#define BATCH 8
#define SEQ   1024
#define HID   768
#define HEADS 6
#define DHEAD 64
#define ALLH  384   // HEADS*DHEAD
#define KS    9
#define PADC  4
#define MROWS (BATCH*SEQ)  // 8192

typedef __attribute__((ext_vector_type(8))) short bf16x8;
typedef __attribute__((ext_vector_type(4))) short bf16x4;
typedef __attribute__((ext_vector_type(4))) float f32x4;

__device__ __forceinline__ ushort f2bf(float x) {   // RTN-even f32 -> bf16 bits
    unsigned u = __float_as_uint(x);
    unsigned r = (u + 0x7FFFu + ((u >> 16) & 1u)) >> 16;
    return (ushort)r;
}
__device__ __forceinline__ unsigned pk2(float a, float b) {
    return (unsigned)f2bf(a) | ((unsigned)f2bf(b) << 16);
}
// TRANS ops via compiler-known paths (hazard handling) -- R7 lesson
__device__ __forceinline__ float fexp2(float x) {
#if __has_builtin(__builtin_amdgcn_exp2f)
    return __builtin_amdgcn_exp2f(x);
#else
    return exp2f(x);
#endif
}
__device__ __forceinline__ float fsqrt(float x) {
#if __has_builtin(__builtin_amdgcn_sqrtf)
    return __builtin_amdgcn_sqrtf(x);
#else
    return __sqrtf(x);
#endif
}
__device__ __forceinline__ unsigned cvtpk(float a, float b) {  // 2 bf16 in 1 instr (RNE, non-trans)
    unsigned r; asm("v_cvt_pk_bf16_f32 %0, %1, %2" : "=v"(r) : "v"(a), "v"(b)); return r;
}

__device__ __forceinline__ void mfma16(f32x4& c4, bf16x4 a, bf16x4 b) {
#if __has_builtin(__builtin_amdgcn_mfma_f32_16x16x16bf16_1k)
    c4 = __builtin_amdgcn_mfma_f32_16x16x16bf16_1k(a, b, c4, 0, 0, 0);
#else
    asm volatile("v_mfma_f32_16x16x16_bf16 %0, %1, %2, %0" : "+v"(c4) : "v"(a), "v"(b));
#endif
}

// ---------------- depthwise conv on K -> bf16, register sliding window ----------------
__global__ __launch_bounds__(256) void dconv_kernel(const float* __restrict__ Kin,
                                                    const float* __restrict__ dw,
                                                    ushort* __restrict__ y) {
    const int t = threadIdx.x;
    const int c4l = t & 63;
    const int sg = t >> 6;
    const int c4 = blockIdx.x * 64 + c4l;
    const int s0 = blockIdx.y * 64 + sg * 16;
    const int b = blockIdx.z;
    const int c = c4 * 4;

    const float* base = Kin + (size_t)b * SEQ * HID + c;
    ushort* ybase = y + (size_t)b * SEQ * HID + c;

    float wv[4][KS];
#pragma unroll
    for (int j = 0; j < 4; ++j)
#pragma unroll
        for (int tt = 0; tt < KS; ++tt) wv[j][tt] = dw[(c + j) * KS + tt];

    float4 win[KS];
#pragma unroll
    for (int tt = 0; tt < KS; ++tt) {
        int sj = s0 - PADC + tt;
        win[tt] = (sj >= 0 && sj < SEQ) ? *reinterpret_cast<const float4*>(base + (size_t)sj * HID)
                                        : float4{0.f, 0.f, 0.f, 0.f};
    }

#pragma unroll
    for (int i = 0; i < 16; ++i) {
        const int s = s0 + i;
        float4 acc = {0.f, 0.f, 0.f, 0.f};
#pragma unroll
        for (int tt = 0; tt < KS; ++tt) {
            acc.x += win[tt].x * wv[0][tt];
            acc.y += win[tt].y * wv[1][tt];
            acc.z += win[tt].z * wv[2][tt];
            acc.w += win[tt].w * wv[3][tt];
        }
        uint2 o;
        o.x = pk2(acc.x, acc.y); o.y = pk2(acc.z, acc.w);
        *reinterpret_cast<uint2*>(ybase + (size_t)s * HID) = o;
#pragma unroll
        for (int tt = 0; tt < KS - 1; ++tt) win[tt] = win[tt + 1];
        int sj = s + 1 + PADC;
        win[KS - 1] = (sj < SEQ) ? *reinterpret_cast<const float4*>(base + (size_t)sj * HID)
                                 : float4{0.f, 0.f, 0.f, 0.f};
    }
}

// ---------------- weight transpose-convert: W[768,384] f32 -> Wt[384,768] bf16 ----------------
__global__ __launch_bounds__(256) void wcvt_kernel(const float* __restrict__ W0, const float* __restrict__ W1,
                                                   const float* __restrict__ W2, const float* __restrict__ W3,
                                                   ushort* __restrict__ O0, ushort* __restrict__ O1,
                                                   ushort* __restrict__ O2, ushort* __restrict__ O3) {
    __shared__ float t[32][33];
    int wsel = blockIdx.z;
    const float* W = wsel == 0 ? W0 : wsel == 1 ? W1 : wsel == 2 ? W2 : W3;
    ushort* O = wsel == 0 ? O0 : wsel == 1 ? O1 : wsel == 2 ? O2 : O3;
    int kt = blockIdx.x * 32;
    int nt = blockIdx.y * 32;
    int tx = threadIdx.x & 31, ty = threadIdx.x >> 5;
#pragma unroll
    for (int i = 0; i < 4; ++i)
        t[ty + i * 8][tx] = W[(size_t)(kt + ty + i * 8) * ALLH + nt + tx];
    __syncthreads();
#pragma unroll
    for (int i = 0; i < 4; ++i)
        O[(size_t)(nt + ty + i * 8) * HID + kt + tx] = f2bf(t[tx][ty + i * 8]);
}

// ---------------- pw convert (already [N=384, K=768]) ----------------
__global__ __launch_bounds__(256) void pwcvt_kernel(const float* __restrict__ pw, ushort* __restrict__ pwb) {
    int i = blockIdx.x * 256 + threadIdx.x;
    if (i < ALLH * HID) pwb[i] = f2bf(pw[i]);
}

// ---------------- merged projection GEMMs, 64x64 tiles, depth-2 register prefetch ----------------
// 5 units x 768 blocks = 3840. Same two-barrier single-buffer loop as R13/R15 (proven);
// loads for step k+2 issued at step k -> ~2 compute phases of latency cover.
__global__ __launch_bounds__(256) void gemm_all(const float* __restrict__ Q,
                                                const float* __restrict__ Kin,
                                                const float* __restrict__ V,
                                                const ushort* __restrict__ ybf,
                                                const ushort* __restrict__ WqT,
                                                const ushort* __restrict__ WkT,
                                                const ushort* __restrict__ WvT,
                                                const ushort* __restrict__ WcoT,
                                                const ushort* __restrict__ pwT,
                                                const float* __restrict__ bco,
                                                const float* __restrict__ sep_bias,
                                                float* __restrict__ qb,
                                                ushort* __restrict__ qh,
                                                ushort* __restrict__ khm,
                                                ushort* __restrict__ vhm,
                                                float* __restrict__ cob,
                                                float* __restrict__ kcb) {
    __shared__ __align__(16) ushort As[64 * 64];
    __shared__ __align__(16) ushort Bs[64 * 64];

    const int bx = blockIdx.x;
    const int swz = (bx & 7) * 480 + (bx >> 3);   // bijective: 3840 = 8*480
    const int unit = swz / 768;
    const int local = swz % 768;
    const int n0 = (local % 6) * 64;
    const int m0 = (local / 6) * 64;

    const float* Af = unit == 0 ? Q : unit == 1 ? Kin : V;   // units 0..3 f32
    const ushort* Ab = ybf;                                   // unit 4 bf16
    const ushort* Bt = unit == 0 ? WqT : unit == 1 ? WkT : unit == 2 ? WvT : unit == 3 ? WcoT : pwT;
    const bool af32 = (unit != 4);

    const int tid = threadIdx.x;
    const int lane = tid & 63;
    const int w = tid >> 6;
    const int g = lane >> 4;
    const int c = lane & 15;

    // staging geometry: thread owns rows r0 and r0+32 at k-chunk c8
    const int r0 = tid >> 3;
    const int r1 = r0 + 32;
    const int c8 = (tid & 7) * 8;
    const int b0 = r0 * 128 + ((c8 * 2) ^ ((r0 & 7) << 4));
    const int b1 = r1 * 128 + ((c8 * 2) ^ ((r1 & 7) << 4));

    struct Regs { uint4 ar0, ar1, br0, br1; float4 f0a, f0b, f1a, f1b; };
    Regs Re, Ro;

    auto loadAB = [&](Regs& R, int k0) {
        if (af32) {
            R.f0a = *reinterpret_cast<const float4*>(&Af[(size_t)(m0 + r0) * HID + k0 + c8]);
            R.f0b = *reinterpret_cast<const float4*>(&Af[(size_t)(m0 + r0) * HID + k0 + c8 + 4]);
            R.f1a = *reinterpret_cast<const float4*>(&Af[(size_t)(m0 + r1) * HID + k0 + c8]);
            R.f1b = *reinterpret_cast<const float4*>(&Af[(size_t)(m0 + r1) * HID + k0 + c8 + 4]);
        } else {
            R.ar0 = *reinterpret_cast<const uint4*>(&Ab[(size_t)(m0 + r0) * HID + k0 + c8]);
            R.ar1 = *reinterpret_cast<const uint4*>(&Ab[(size_t)(m0 + r1) * HID + k0 + c8]);
        }
        R.br0 = *reinterpret_cast<const uint4*>(&Bt[(size_t)(n0 + r0) * HID + k0 + c8]);
        R.br1 = *reinterpret_cast<const uint4*>(&Bt[(size_t)(n0 + r1) * HID + k0 + c8]);
    };
    auto stage = [&](const Regs& R) {
        if (af32) {
            uint4 p0, p1;
            p0.x = pk2(R.f0a.x, R.f0a.y); p0.y = pk2(R.f0a.z, R.f0a.w);
            p0.z = pk2(R.f0b.x, R.f0b.y); p0.w = pk2(R.f0b.z, R.f0b.w);
            p1.x = pk2(R.f1a.x, R.f1a.y); p1.y = pk2(R.f1a.z, R.f1a.w);
            p1.z = pk2(R.f1b.x, R.f1b.y); p1.w = pk2(R.f1b.z, R.f1b.w);
            *reinterpret_cast<uint4*>((char*)As + b0) = p0;
            *reinterpret_cast<uint4*>((char*)As + b1) = p1;
        } else {
            *reinterpret_cast<uint4*>((char*)As + b0) = R.ar0;
            *reinterpret_cast<uint4*>((char*)As + b1) = R.ar1;
        }
        *reinterpret_cast<uint4*>((char*)Bs + b0) = R.br0;
        *reinterpret_cast<uint4*>((char*)Bs + b1) = R.br1;
    };

    f32x4 acc[4] = {{0,0,0,0},{0,0,0,0},{0,0,0,0},{0,0,0,0}};
    const int arow = w * 16 + c;
    const int asw = (arow & 7) << 4;

    auto compute = [&]() {
        bf16x8 af0 = *reinterpret_cast<const bf16x8*>((char*)As + arow * 128 + ((g * 16) ^ asw));
        bf16x8 af1 = *reinterpret_cast<const bf16x8*>((char*)As + arow * 128 + ((64 + g * 16) ^ asw));
#pragma unroll
        for (int nq = 0; nq < 4; ++nq) {
            const int brow = nq * 16 + c;
            const int bsw = (brow & 7) << 4;
            bf16x8 bf0 = *reinterpret_cast<const bf16x8*>((char*)Bs + brow * 128 + ((g * 16) ^ bsw));
            bf16x8 bf1 = *reinterpret_cast<const bf16x8*>((char*)Bs + brow * 128 + ((64 + g * 16) ^ bsw));
            acc[nq] = __builtin_amdgcn_mfma_f32_16x16x32_bf16(af0, bf0, acc[nq], 0, 0, 0);
            acc[nq] = __builtin_amdgcn_mfma_f32_16x16x32_bf16(af1, bf1, acc[nq], 0, 0, 0);
        }
    };

    loadAB(Re, 0);
    loadAB(Ro, 64);
#pragma unroll
    for (int ksp = 0; ksp < 12; ksp += 2) {
        __syncthreads();                          // prev compute done reading LDS
        stage(Re);
        __syncthreads();                          // writes visible
        if (ksp + 2 < 12) loadAB(Re, (ksp + 2) * 64);
        compute();
        __syncthreads();
        stage(Ro);
        __syncthreads();
        if (ksp + 3 < 12) loadAB(Ro, (ksp + 3) * 64);
        compute();
    }

    // ---------------- epilogues (R13-verbatim formulas) ----------------
    if (unit == 2) {
        // V@Wv -> transposed+swizzled 64x64 tiles [d-row][key-col]
        const int head = n0 >> 6;
        const int bb = m0 >> 10;
        const int st = (m0 & 1023) >> 6;
        char* tb = (char*)vhm + (((size_t)(bb * HEADS + head) * 16 + st) * 4096) * 2;
#pragma unroll
        for (int nq = 0; nq < 4; ++nq) {
            const int d = nq * 16 + c;
            unsigned off = (unsigned)d * 128 + (((unsigned)(32 * w + 8 * g)) ^ ((d & 7) << 4));
            uint2 vv;
            vv.x = pk2(acc[nq][0], acc[nq][1]);
            vv.y = pk2(acc[nq][2], acc[nq][3]);
            *reinterpret_cast<uint2*>(tb + off) = vv;
        }
        return;
    }

#pragma unroll
    for (int nq = 0; nq < 4; ++nq) {
        const int n = n0 + nq * 16 + c;
        float bv = 0.f;
        if (unit == 3) bv = bco[n];
        if (unit == 4) bv = sep_bias[n];
#pragma unroll
        for (int r = 0; r < 4; ++r) {
            const int m = m0 + w * 16 + g * 4 + r;
            float v = acc[nq][r] + bv;
            if (unit == 0) {
                qb[(size_t)m * ALLH + n] = v;
                int bb = m >> 10, s = m & 1023;
                int head = n >> 6, d = n & 63;
                qh[(((size_t)bb * HEADS + head) * SEQ + s) * 64 + d] = f2bf(v);
            } else if (unit == 1) {
                int bb = m >> 10, s = m & 1023;
                int head = n >> 6, d = n & 63;
                char* tb = (char*)khm + (((size_t)(bb * HEADS + head) * 16 + (s >> 6)) * 4096) * 2;
                unsigned off = (unsigned)(s & 63) * 128 + (((unsigned)(d * 2)) ^ ((s & 7) << 4));
                *reinterpret_cast<ushort*>(tb + off) = f2bf(v);
            } else if (unit == 3) {
                cob[(size_t)m * ALLH + n] = v;
            } else {  // unit 4
                kcb[(size_t)m * ALLH + n] = v;
            }
        }
    }
}

// ---------------- span kernel (float4 dot loop) ----------------
__global__ __launch_bounds__(256) void spankern_kernel(const float* __restrict__ keyconv,
                                                       const float* __restrict__ q,
                                                       const float* __restrict__ Wck,
                                                       const float* __restrict__ bck,
                                                       float* __restrict__ kern_sm) {
    __shared__ __align__(16) float ca[4][ALLH];
    __shared__ float kv[4][64];
    int row0 = blockIdx.x * 4;
    int tid = threadIdx.x;
    int r = tid >> 6;
    int lane = tid & 63;
    int row = row0 + r;
    for (int e = lane; e < ALLH / 4; e += 64) {
        size_t off = (size_t)row * ALLH + e * 4;
        const float4 kc = *reinterpret_cast<const float4*>(&keyconv[off]);
        const float4 qq = *reinterpret_cast<const float4*>(&q[off]);
        float4 p; p.x = kc.x * qq.x; p.y = kc.y * qq.y; p.z = kc.z * qq.z; p.w = kc.w * qq.w;
        *reinterpret_cast<float4*>(&ca[r][e * 4]) = p;
    }
    __syncthreads();
    float val = 0.f;
    if (lane < HEADS * KS) {
#pragma unroll 4
        for (int k4 = 0; k4 < ALLH / 4; ++k4) {
            const float4 cav = *reinterpret_cast<const float4*>(&ca[r][k4 * 4]);
            val += cav.x * Wck[(k4 * 4 + 0) * (HEADS * KS) + lane];
            val += cav.y * Wck[(k4 * 4 + 1) * (HEADS * KS) + lane];
            val += cav.z * Wck[(k4 * 4 + 2) * (HEADS * KS) + lane];
            val += cav.w * Wck[(k4 * 4 + 3) * (HEADS * KS) + lane];
        }
        val += bck[lane];
    }
    kv[r][lane] = val;
    __syncthreads();
    if (lane < HEADS) {
        float mx = -INFINITY;
#pragma unroll
        for (int t = 0; t < KS; ++t) mx = fmaxf(mx, kv[r][lane * KS + t]);
        float e[KS];
        float sum = 0.f;
#pragma unroll
        for (int t = 0; t < KS; ++t) {
            e[t] = expf(kv[r][lane * KS + t] - mx);
            sum += e[t];
        }
        float inv = 1.f / sum;
#pragma unroll
        for (int t = 0; t < KS; ++t)
            kern_sm[((size_t)row * HEADS + lane) * KS + t] = e[t] * inv;
    }
}

// ---------------- conv_out: register sliding window (8 positions/thread) ----------------
__global__ __launch_bounds__(256) void convout_kernel(const float* __restrict__ co,
                                                      const float* __restrict__ kern_sm,
                                                      float* __restrict__ out) {
    const int t = threadIdx.x;
    const int c4l = t & 31;                  // 32 consecutive c4 -> 512B coalesced rows
    const int sg = t >> 5;                   // 0..7
    const int c4 = blockIdx.x * 32 + c4l;    // 0..95
    const int s0 = (blockIdx.y * 8 + sg) * 8;
    const int b = blockIdx.z;
    const int c = c4 * 4;
    const int h = c >> 6;

    const float* base = co + (size_t)b * SEQ * ALLH + c;
    float* obase = out + (size_t)b * SEQ * (2 * ALLH) + ALLH + c;
    const float* kbase = kern_sm + ((size_t)b * SEQ) * (HEADS * KS) + h * KS;

    float4 win[KS];
#pragma unroll
    for (int tt = 0; tt < KS; ++tt) {
        int sj = s0 - PADC + tt;
        win[tt] = (sj >= 0 && sj < SEQ) ? *reinterpret_cast<const float4*>(base + (size_t)sj * ALLH)
                                        : float4{0.f, 0.f, 0.f, 0.f};
    }

#pragma unroll
    for (int i = 0; i < 8; ++i) {
        const int s = s0 + i;
        const float* kr = kbase + (size_t)s * (HEADS * KS);
        float4 acc = {0.f, 0.f, 0.f, 0.f};
#pragma unroll
        for (int tt = 0; tt < KS; ++tt) {
            const float kt = kr[tt];
            acc.x += win[tt].x * kt;
            acc.y += win[tt].y * kt;
            acc.z += win[tt].z * kt;
            acc.w += win[tt].w * kt;
        }
        *reinterpret_cast<float4*>(obase + (size_t)s * (2 * ALLH)) = acc;
#pragma unroll
        for (int tt = 0; tt < KS - 1; ++tt) win[tt] = win[tt + 1];
        int sj = s + 1 + PADC;
        win[KS - 1] = (sj < SEQ) ? *reinterpret_cast<const float4*>(base + (size_t)sj * ALLH)
                                 : float4{0.f, 0.f, 0.f, 0.f};
    }
}

// ---------------- fused monotonic attention (MFMA, pre-swizzled tiles; verbatim R10/R12/R13) ----------------
__global__ __launch_bounds__(256) void attn_mfma(const ushort* __restrict__ qh,
                                                 const ushort* __restrict__ kh,
                                                 const ushort* __restrict__ vh,
                                                 const int* __restrict__ mask,
                                                 const float* __restrict__ gammas,
                                                 float* __restrict__ out) {
    __shared__ __align__(16) ushort kbuf[64 * 64];   // swizzled [key][d] tile (copied verbatim)
    __shared__ __align__(16) ushort vbuf[64 * 64];   // transposed+swizzled [d][key] tile
    __shared__ float s_msk[SEQ];

    const int bid = blockIdx.x;
    const int blk = (bid & 7) * 96 + (bid >> 3);
    const int qt = blk & 15;
    const int h = (blk >> 4) % HEADS;
    const int b = blk / (16 * HEADS);
    const int i0 = qt * 64;
    const int tid = threadIdx.x;
    const int lane = tid & 63;
    const int w = tid >> 6;
    const int g = lane >> 4;
    const int c = lane & 15;

    const float LOG2E = 1.44269504f;
    float g0 = gammas[h];
    float gamma2 = -(fmaxf(g0, 0.f) + log1pf(expf(-fabsf(g0)))) * LOG2E;  // -softplus * log2e
    const float SLOG2 = 0.125f * LOG2E;

    const ushort* ktiles = kh + ((size_t)(b * HEADS + h) * 16) * 4096;
    const ushort* vtiles = vh + ((size_t)(b * HEADS + h) * 16) * 4096;
    const ushort* qhb = qh + ((size_t)b * HEADS + h) * SEQ * 64;

    for (int e = tid; e < SEQ; e += 256)
        s_msk[e] = (mask[b * SEQ + e] != 0) ? 1.f : 0.f;

    // Q B-fragments
    bf16x8 qf0, qf1;
    {
        const ushort* qrow = qhb + (size_t)(i0 + w * 16 + c) * 64 + g * 8;
        qf0 = *reinterpret_cast<const bf16x8*>(qrow);
        qf1 = *reinterpret_cast<const bf16x8*>(qrow + 32);
    }

    // ================= pass 1: raw denominator T =================
    float Tacc = 0.f;
    for (int chk = 0; chk < 16; ++chk) {
        __syncthreads();
        const ushort* ktp = ktiles + chk * 4096;
#pragma unroll
        for (int it = 0; it < 2; ++it) {
            int e16 = (tid + it * 256) * 16;
            *reinterpret_cast<uint4*>((char*)kbuf + e16) =
                *reinterpret_cast<const uint4*>((const char*)ktp + e16);
        }
        __syncthreads();
        const int j0 = chk * 64;
#pragma unroll
        for (int m = 0; m < 4; ++m) {
            f32x4 acc = {0.f, 0.f, 0.f, 0.f};
            int row = m * 16 + c;
            int sw = (row & 7) << 4;
            bf16x8 kf0 = *reinterpret_cast<const bf16x8*>((char*)kbuf + row * 128 + ((g * 16) ^ sw));
            bf16x8 kf1 = *reinterpret_cast<const bf16x8*>((char*)kbuf + row * 128 + ((64 + g * 16) ^ sw));
            acc = __builtin_amdgcn_mfma_f32_16x16x32_bf16(kf0, qf0, acc, 0, 0, 0);
            acc = __builtin_amdgcn_mfma_f32_16x16x32_bf16(kf1, qf1, acc, 0, 0, 0);
#pragma unroll
            for (int r = 0; r < 4; ++r) {
                float mk = s_msk[j0 + m * 16 + g * 4 + r];
                Tacc += mk * fexp2(acc[r] * SLOG2);
            }
        }
    }
    Tacc += __shfl_xor(Tacc, 16, 64);
    Tacc += __shfl_xor(Tacc, 32, 64);
    const float T = Tacc;
    const float invT = (T > 0.f) ? 1.f / T : 0.f;

    // ================= pass 2: cum, effect, second softmax, PV =================
    f32x4 ctx0 = {0,0,0,0}, ctx1 = {0,0,0,0}, ctx2 = {0,0,0,0}, ctx3 = {0,0,0,0};
    float l2acc = 0.f;
    float base = 0.f;
    const float iq = (float)(i0 + w * 16 + c);
    const unsigned vx = (unsigned)((c & 7) << 4);    // lane-const read swizzle

    for (int chk = 0; chk < 16; ++chk) {
        __syncthreads();
        const ushort* ktp = ktiles + chk * 4096;
        const ushort* vtp = vtiles + chk * 4096;
#pragma unroll
        for (int it = 0; it < 2; ++it) {
            int e16 = (tid + it * 256) * 16;
            *reinterpret_cast<uint4*>((char*)kbuf + e16) =
                *reinterpret_cast<const uint4*>((const char*)ktp + e16);
            *reinterpret_cast<uint4*>((char*)vbuf + e16) =
                *reinterpret_cast<const uint4*>((const char*)vtp + e16);
        }
        __syncthreads();
        const int j0 = chk * 64;
#pragma unroll
        for (int m = 0; m < 4; ++m) {
            f32x4 acc = {0.f, 0.f, 0.f, 0.f};
            int row = m * 16 + c;
            int sw = (row & 7) << 4;
            bf16x8 kf0 = *reinterpret_cast<const bf16x8*>((char*)kbuf + row * 128 + ((g * 16) ^ sw));
            bf16x8 kf1 = *reinterpret_cast<const bf16x8*>((char*)kbuf + row * 128 + ((64 + g * 16) ^ sw));
            acc = __builtin_amdgcn_mfma_f32_16x16x32_bf16(kf0, qf0, acc, 0, 0, 0);
            acc = __builtin_amdgcn_mfma_f32_16x16x32_bf16(kf1, qf1, acc, 0, 0, 0);

            float sl[4], mk[4], incl[4];
            float li = 0.f;
#pragma unroll
            for (int r = 0; r < 4; ++r) {
                mk[r] = s_msk[j0 + m * 16 + g * 4 + r];
                sl[r] = acc[r] * SLOG2;                 // score in log2 units
                float e = mk[r] * fexp2(sl[r]);
                li += e;
                incl[r] = li;
            }
            float gs = li;
            float up = __shfl_up(gs, 16, 64); if (g >= 1) gs += up;
            up = __shfl_up(gs, 32, 64); if (g >= 2) gs += up;
            float gexcl = gs - li;
            float ttot = __shfl(gs, 48 + c, 64);

            const float dbase = iq - (float)(j0 + m * 16 + g * 4);
            float p2[4];
#pragma unroll
            for (int r = 0; r < 4; ++r) {
                float cum = base + gexcl + incl[r];
                float rem = fmaxf(1.0f - cum * invT, 0.f);
                float pos = fabsf(dbase - (float)r);
                float dist = fsqrt(rem * pos);
                float eff = fmaxf(fexp2(dist * gamma2), 1e-5f);  // gamma2<0, dist>=0 -> eff<=1
                p2[r] = mk[r] * fexp2(sl[r] * eff);
                l2acc += p2[r];
            }
            base += ttot;

            union { uint2 u; bf16x4 v; } pu;
            pu.u.x = cvtpk(p2[0], p2[1]);
            pu.u.y = cvtpk(p2[2], p2[3]);
            bf16x4 pa = pu.v;

            const unsigned cb = ((unsigned)(32 * m + 8 * g)) ^ vx;
#pragma unroll
            for (int t = 0; t < 4; ++t) {
                bf16x4 vfrag = *reinterpret_cast<const bf16x4*>((char*)vbuf + (unsigned)(c + 16 * t) * 128 + cb);
                if (t == 0) mfma16(ctx0, pa, vfrag);
                else if (t == 1) mfma16(ctx1, pa, vfrag);
                else if (t == 2) mfma16(ctx2, pa, vfrag);
                else mfma16(ctx3, pa, vfrag);
            }
        }
    }
    l2acc += __shfl_xor(l2acc, 16, 64);
    l2acc += __shfl_xor(l2acc, 32, 64);
    const float invl2 = 1.f / l2acc;

#pragma unroll
    for (int r = 0; r < 4; ++r) {
        float inv_r = __shfl(invl2, g * 4 + r, 64);
        int qrow = i0 + w * 16 + g * 4 + r;
        float* orow = out + ((size_t)b * SEQ + qrow) * (2 * ALLH) + h * DHEAD;
        orow[c +  0] = ctx0[r] * inv_r;
        orow[c + 16] = ctx1[r] * inv_r;
        orow[c + 32] = ctx2[r] * inv_r;
        orow[c + 48] = ctx3[r] * inv_r;
    }
}

// ---------------- launch ----------------
extern "C" void kernel_launch(void* const* d_in, const int* in_sizes, int n_in,
                              void* d_out, int out_size, void* d_ws, size_t ws_size,
                              hipStream_t stream) {
    const float* Q = (const float*)d_in[0];
    const float* Kin = (const float*)d_in[1];
    const float* V = (const float*)d_in[2];
    const float* Wq = (const float*)d_in[3];
    const float* Wk = (const float*)d_in[4];
    const float* Wv = (const float*)d_in[5];
    const float* dw = (const float*)d_in[6];
    const float* pw = (const float*)d_in[7];
    const float* sep_bias = (const float*)d_in[8];
    const float* Wck = (const float*)d_in[9];
    const float* bck = (const float*)d_in[10];
    const float* Wco = (const float*)d_in[11];
    const float* bco = (const float*)d_in[12];
    const float* gammas = (const float*)d_in[13];
    const int* mask = (const int*)d_in[14];
    float* out = (float*)d_out;
    float* ws = (float*)d_ws;

    const size_t NP = (size_t)MROWS * ALLH;        // 3145728
    const size_t WSZ = (size_t)ALLH * HID;         // 294912
    float* qb   = ws;                              // f32 q (spankern)
    float* cob  = qb + NP;
    float* kcb  = cob + NP;
    float* kern = kcb + NP;                        // 8192*54
    ushort* qh  = (ushort*)(kern + (size_t)MROWS * HEADS * KS);
    ushort* khm = qh + NP;                         // swizzled K tiles
    ushort* vhm = khm + NP;                        // transposed+swizzled V tiles
    ushort* ybf = vhm + NP;                        // dconv out bf16 [8192][768]
    ushort* WqT = ybf + (size_t)MROWS * HID;
    ushort* WkT = WqT + WSZ;
    ushort* WvT = WkT + WSZ;
    ushort* WcoT = WvT + WSZ;
    ushort* pwT = WcoT + WSZ;

    // 1. depthwise conv (register sliding window) + weight conversions
    dconv_kernel<<<dim3(3, 16, BATCH), 256, 0, stream>>>(Kin, dw, ybf);
    wcvt_kernel<<<dim3(24, 12, 4), 256, 0, stream>>>(Wq, Wk, Wv, Wco, WqT, WkT, WvT, WcoT);
    pwcvt_kernel<<<(ALLH * HID + 255) / 256, 256, 0, stream>>>(pw, pwT);

    // 2. all five projection GEMMs, one dispatch, depth-2 register prefetch
    gemm_all<<<3840, 256, 0, stream>>>(Q, Kin, V, ybf, WqT, WkT, WvT, WcoT, pwT,
                                       bco, sep_bias, qb, qh, khm, vhm, cob, kcb);

    // 3. span-dynamic-conv kernel weights + softmax
    spankern_kernel<<<MROWS / 4, 256, 0, stream>>>(kcb, qb, Wck, bck, kern);

    // 4. conv branch output (channels 384..767), register sliding window
    convout_kernel<<<dim3(3, 16, BATCH), 256, 0, stream>>>(cob, kern, out);

    // 5. fused monotonic attention (channels 0..383)
    attn_mfma<<<BATCH * HEADS * (SEQ / 64), 256, 0, stream>>>(qh, khm, vhm, mask, gammas, out);
}

// Round 17
// 223.251 us; speedup vs baseline: 2.3579x; 2.3579x over previous
//
#include <hip/hip_runtime.h>
#include <math.h>

#define BATCH 8
#define SEQ   1024
#define HID   768
#define HEADS 6
#define DHEAD 64
#define ALLH  384   // HEADS*DHEAD
#define KS    9
#define PADC  4
#define MROWS (BATCH*SEQ)  // 8192

typedef __attribute__((ext_vector_type(8))) short bf16x8;
typedef __attribute__((ext_vector_type(4))) short bf16x4;
typedef __attribute__((ext_vector_type(4))) float f32x4;

__device__ __forceinline__ ushort f2bf(float x) {   // RTN-even f32 -> bf16 bits
    unsigned u = __float_as_uint(x);
    unsigned r = (u + 0x7FFFu + ((u >> 16) & 1u)) >> 16;
    return (ushort)r;
}
__device__ __forceinline__ unsigned pk2(float a, float b) {
    return (unsigned)f2bf(a) | ((unsigned)f2bf(b) << 16);
}
// TRANS ops via compiler-known paths (hazard handling) -- R7 lesson
__device__ __forceinline__ float fexp2(float x) {
#if __has_builtin(__builtin_amdgcn_exp2f)
    return __builtin_amdgcn_exp2f(x);
#else
    return exp2f(x);
#endif
}
__device__ __forceinline__ float fsqrt(float x) {
#if __has_builtin(__builtin_amdgcn_sqrtf)
    return __builtin_amdgcn_sqrtf(x);
#else
    return __sqrtf(x);
#endif
}
__device__ __forceinline__ unsigned cvtpk(float a, float b) {  // 2 bf16 in 1 instr (RNE, non-trans)
    unsigned r; asm("v_cvt_pk_bf16_f32 %0, %1, %2" : "=v"(r) : "v"(a), "v"(b)); return r;
}

__device__ __forceinline__ void mfma16(f32x4& c4, bf16x4 a, bf16x4 b) {
#if __has_builtin(__builtin_amdgcn_mfma_f32_16x16x16bf16_1k)
    c4 = __builtin_amdgcn_mfma_f32_16x16x16bf16_1k(a, b, c4, 0, 0, 0);
#else
    asm volatile("v_mfma_f32_16x16x16_bf16 %0, %1, %2, %0" : "+v"(c4) : "v"(a), "v"(b));
#endif
}

// ---------------- depthwise conv on K -> bf16, register sliding window ----------------
__global__ __launch_bounds__(256) void dconv_kernel(const float* __restrict__ Kin,
                                                    const float* __restrict__ dw,
                                                    ushort* __restrict__ y) {
    const int t = threadIdx.x;
    const int c4l = t & 63;
    const int sg = t >> 6;
    const int c4 = blockIdx.x * 64 + c4l;
    const int s0 = blockIdx.y * 64 + sg * 16;
    const int b = blockIdx.z;
    const int c = c4 * 4;

    const float* base = Kin + (size_t)b * SEQ * HID + c;
    ushort* ybase = y + (size_t)b * SEQ * HID + c;

    float wv[4][KS];
#pragma unroll
    for (int j = 0; j < 4; ++j)
#pragma unroll
        for (int tt = 0; tt < KS; ++tt) wv[j][tt] = dw[(c + j) * KS + tt];

    float4 win[KS];
#pragma unroll
    for (int tt = 0; tt < KS; ++tt) {
        int sj = s0 - PADC + tt;
        win[tt] = (sj >= 0 && sj < SEQ) ? *reinterpret_cast<const float4*>(base + (size_t)sj * HID)
                                        : float4{0.f, 0.f, 0.f, 0.f};
    }

#pragma unroll
    for (int i = 0; i < 16; ++i) {
        const int s = s0 + i;
        float4 acc = {0.f, 0.f, 0.f, 0.f};
#pragma unroll
        for (int tt = 0; tt < KS; ++tt) {
            acc.x += win[tt].x * wv[0][tt];
            acc.y += win[tt].y * wv[1][tt];
            acc.z += win[tt].z * wv[2][tt];
            acc.w += win[tt].w * wv[3][tt];
        }
        uint2 o;
        o.x = pk2(acc.x, acc.y); o.y = pk2(acc.z, acc.w);
        *reinterpret_cast<uint2*>(ybase + (size_t)s * HID) = o;
#pragma unroll
        for (int tt = 0; tt < KS - 1; ++tt) win[tt] = win[tt + 1];
        int sj = s + 1 + PADC;
        win[KS - 1] = (sj < SEQ) ? *reinterpret_cast<const float4*>(base + (size_t)sj * HID)
                                 : float4{0.f, 0.f, 0.f, 0.f};
    }
}

// ---------------- weight transpose-convert: W[768,384] f32 -> Wt[384,768] bf16 ----------------
__global__ __launch_bounds__(256) void wcvt_kernel(const float* __restrict__ W0, const float* __restrict__ W1,
                                                   const float* __restrict__ W2, const float* __restrict__ W3,
                                                   ushort* __restrict__ O0, ushort* __restrict__ O1,
                                                   ushort* __restrict__ O2, ushort* __restrict__ O3) {
    __shared__ float t[32][33];
    int wsel = blockIdx.z;
    const float* W = wsel == 0 ? W0 : wsel == 1 ? W1 : wsel == 2 ? W2 : W3;
    ushort* O = wsel == 0 ? O0 : wsel == 1 ? O1 : wsel == 2 ? O2 : O3;
    int kt = blockIdx.x * 32;
    int nt = blockIdx.y * 32;
    int tx = threadIdx.x & 31, ty = threadIdx.x >> 5;
#pragma unroll
    for (int i = 0; i < 4; ++i)
        t[ty + i * 8][tx] = W[(size_t)(kt + ty + i * 8) * ALLH + nt + tx];
    __syncthreads();
#pragma unroll
    for (int i = 0; i < 4; ++i)
        O[(size_t)(nt + ty + i * 8) * HID + kt + tx] = f2bf(t[tx][ty + i * 8]);
}

// ---------------- pw convert (already [N=384, K=768]) ----------------
__global__ __launch_bounds__(256) void pwcvt_kernel(const float* __restrict__ pw, ushort* __restrict__ pwb) {
    int i = blockIdx.x * 256 + threadIdx.x;
    if (i < ALLH * HID) pwb[i] = f2bf(pw[i]);
}

// ---------------- merged projection GEMMs, 128x128 tiles, 1-phase (R14-proven) ----------------
// 5 units x 192 blocks = 960. unit: 0=Q->qb+qh, 1=K->khm tiles, 2=V@Wv->vhm tiles,
// 3=V@Wco->cob(+bco), 4=ybf@pw->kcb(+sep_bias). Wave w -> 64x64 quadrant (wr=w>>1, wc=w&1).
__global__ __launch_bounds__(256) void gemm_all(const float* __restrict__ Q,
                                                const float* __restrict__ Kin,
                                                const float* __restrict__ V,
                                                const ushort* __restrict__ ybf,
                                                const ushort* __restrict__ WqT,
                                                const ushort* __restrict__ WkT,
                                                const ushort* __restrict__ WvT,
                                                const ushort* __restrict__ WcoT,
                                                const ushort* __restrict__ pwT,
                                                const float* __restrict__ bco,
                                                const float* __restrict__ sep_bias,
                                                float* __restrict__ qb,
                                                ushort* __restrict__ qh,
                                                ushort* __restrict__ khm,
                                                ushort* __restrict__ vhm,
                                                float* __restrict__ cob,
                                                float* __restrict__ kcb) {
    __shared__ __align__(16) ushort As[128 * 64];
    __shared__ __align__(16) ushort Bs[128 * 64];

    const int bx = blockIdx.x;
    const int swz = (bx & 7) * 120 + (bx >> 3);   // bijective: 960 = 8*120
    const int unit = swz / 192;
    const int local = swz % 192;
    const int n0 = (local % 3) * 128;
    const int m0 = (local / 3) * 128;

    const float* Af = unit == 0 ? Q : unit == 1 ? Kin : V;   // units 0..3 f32
    const ushort* Ab = ybf;                                   // unit 4 bf16
    const ushort* Bt = unit == 0 ? WqT : unit == 1 ? WkT : unit == 2 ? WvT : unit == 3 ? WcoT : pwT;
    const bool af32 = (unit != 4);

    const int tid = threadIdx.x;
    const int lane = tid & 63;
    const int w = tid >> 6;
    const int wr = w >> 1, wc = w & 1;
    const int g = lane >> 4;
    const int c = lane & 15;

    f32x4 acc[4][4];
#pragma unroll
    for (int i = 0; i < 4; ++i)
#pragma unroll
        for (int j = 0; j < 4; ++j) acc[i][j] = f32x4{0.f, 0.f, 0.f, 0.f};

    for (int k0 = 0; k0 < HID; k0 += 64) {
        __syncthreads();
#pragma unroll
        for (int it = 0; it < 4; ++it) {
            int e = tid + it * 256;            // 0..1023
            int row = e >> 3;                  // 0..127
            int c8 = (e & 7) * 8;
            int boff = row * 128 + ((c8 * 2) ^ ((row & 7) << 4));
            if (af32) {
                const float4 f0 = *reinterpret_cast<const float4*>(&Af[(size_t)(m0 + row) * HID + k0 + c8]);
                const float4 f1 = *reinterpret_cast<const float4*>(&Af[(size_t)(m0 + row) * HID + k0 + c8 + 4]);
                uint4 p;
                p.x = pk2(f0.x, f0.y); p.y = pk2(f0.z, f0.w);
                p.z = pk2(f1.x, f1.y); p.w = pk2(f1.z, f1.w);
                *reinterpret_cast<uint4*>((char*)As + boff) = p;
            } else {
                const uint4 av = *reinterpret_cast<const uint4*>(&Ab[(size_t)(m0 + row) * HID + k0 + c8]);
                *reinterpret_cast<uint4*>((char*)As + boff) = av;
            }
            const uint4 bv = *reinterpret_cast<const uint4*>(&Bt[(size_t)(n0 + row) * HID + k0 + c8]);
            *reinterpret_cast<uint4*>((char*)Bs + boff) = bv;
        }
        __syncthreads();

        bf16x8 af0[4], af1[4];
#pragma unroll
        for (int mq = 0; mq < 4; ++mq) {
            const int arow = wr * 64 + mq * 16 + c;
            const int asw = (arow & 7) << 4;
            af0[mq] = *reinterpret_cast<const bf16x8*>((char*)As + arow * 128 + ((g * 16) ^ asw));
            af1[mq] = *reinterpret_cast<const bf16x8*>((char*)As + arow * 128 + ((64 + g * 16) ^ asw));
        }
#pragma unroll
        for (int nq = 0; nq < 4; ++nq) {
            const int brow = wc * 64 + nq * 16 + c;
            const int bsw = (brow & 7) << 4;
            bf16x8 bf0 = *reinterpret_cast<const bf16x8*>((char*)Bs + brow * 128 + ((g * 16) ^ bsw));
            bf16x8 bf1 = *reinterpret_cast<const bf16x8*>((char*)Bs + brow * 128 + ((64 + g * 16) ^ bsw));
#pragma unroll
            for (int mq = 0; mq < 4; ++mq) {
                acc[mq][nq] = __builtin_amdgcn_mfma_f32_16x16x32_bf16(af0[mq], bf0, acc[mq][nq], 0, 0, 0);
                acc[mq][nq] = __builtin_amdgcn_mfma_f32_16x16x32_bf16(af1[mq], bf1, acc[mq][nq], 0, 0, 0);
            }
        }
    }

    // ---------------- epilogues ----------------
    if (unit == 2) {
        // V@Wv -> transposed+swizzled 64x64 tiles [d-row][key-col]
#pragma unroll
        for (int mq = 0; mq < 4; ++mq) {
            const int mbase = m0 + wr * 64 + mq * 16 + g * 4;   // key of acc[mq][nq][0]
            const int bb = mbase >> 10;
            const int st = (mbase & 1023) >> 6;
            const unsigned colb = (unsigned)(32 * mq + 8 * g);  // 2*(key&63) base
#pragma unroll
            for (int nq = 0; nq < 4; ++nq) {
                const int n = n0 + wc * 64 + nq * 16 + c;
                const int head = n >> 6;
                const int d = n & 63;
                char* tb = (char*)vhm + (((size_t)(bb * HEADS + head) * 16 + st) * 4096) * 2;
                unsigned off = (unsigned)d * 128 + (colb ^ ((d & 7) << 4));
                uint2 vv;
                vv.x = pk2(acc[mq][nq][0], acc[mq][nq][1]);
                vv.y = pk2(acc[mq][nq][2], acc[mq][nq][3]);
                *reinterpret_cast<uint2*>(tb + off) = vv;
            }
        }
        return;
    }

#pragma unroll
    for (int nq = 0; nq < 4; ++nq) {
        const int n = n0 + wc * 64 + nq * 16 + c;
        float bv = 0.f;
        if (unit == 3) bv = bco[n];
        if (unit == 4) bv = sep_bias[n];
#pragma unroll
        for (int mq = 0; mq < 4; ++mq) {
#pragma unroll
            for (int r = 0; r < 4; ++r) {
                const int m = m0 + wr * 64 + mq * 16 + g * 4 + r;
                float v = acc[mq][nq][r] + bv;
                if (unit == 0) {
                    qb[(size_t)m * ALLH + n] = v;
                    int bb = m >> 10, s = m & 1023;
                    int head = n >> 6, d = n & 63;
                    qh[(((size_t)bb * HEADS + head) * SEQ + s) * 64 + d] = f2bf(v);
                } else if (unit == 1) {
                    int bb = m >> 10, s = m & 1023;
                    int head = n >> 6, d = n & 63;
                    char* tb = (char*)khm + (((size_t)(bb * HEADS + head) * 16 + (s >> 6)) * 4096) * 2;
                    unsigned off = (unsigned)(s & 63) * 128 + (((unsigned)(d * 2)) ^ ((s & 7) << 4));
                    *reinterpret_cast<ushort*>(tb + off) = f2bf(v);
                } else if (unit == 3) {
                    cob[(size_t)m * ALLH + n] = v;
                } else {  // unit 4
                    kcb[(size_t)m * ALLH + n] = v;
                }
            }
        }
    }
}

// ---------------- span kernel (float4 dot loop) ----------------
__global__ __launch_bounds__(256) void spankern_kernel(const float* __restrict__ keyconv,
                                                       const float* __restrict__ q,
                                                       const float* __restrict__ Wck,
                                                       const float* __restrict__ bck,
                                                       float* __restrict__ kern_sm) {
    __shared__ __align__(16) float ca[4][ALLH];
    __shared__ float kv[4][64];
    int row0 = blockIdx.x * 4;
    int tid = threadIdx.x;
    int r = tid >> 6;
    int lane = tid & 63;
    int row = row0 + r;
    for (int e = lane; e < ALLH / 4; e += 64) {
        size_t off = (size_t)row * ALLH + e * 4;
        const float4 kc = *reinterpret_cast<const float4*>(&keyconv[off]);
        const float4 qq = *reinterpret_cast<const float4*>(&q[off]);
        float4 p; p.x = kc.x * qq.x; p.y = kc.y * qq.y; p.z = kc.z * qq.z; p.w = kc.w * qq.w;
        *reinterpret_cast<float4*>(&ca[r][e * 4]) = p;
    }
    __syncthreads();
    float val = 0.f;
    if (lane < HEADS * KS) {
#pragma unroll 4
        for (int k4 = 0; k4 < ALLH / 4; ++k4) {
            const float4 cav = *reinterpret_cast<const float4*>(&ca[r][k4 * 4]);
            val += cav.x * Wck[(k4 * 4 + 0) * (HEADS * KS) + lane];
            val += cav.y * Wck[(k4 * 4 + 1) * (HEADS * KS) + lane];
            val += cav.z * Wck[(k4 * 4 + 2) * (HEADS * KS) + lane];
            val += cav.w * Wck[(k4 * 4 + 3) * (HEADS * KS) + lane];
        }
        val += bck[lane];
    }
    kv[r][lane] = val;
    __syncthreads();
    if (lane < HEADS) {
        float mx = -INFINITY;
#pragma unroll
        for (int t = 0; t < KS; ++t) mx = fmaxf(mx, kv[r][lane * KS + t]);
        float e[KS];
        float sum = 0.f;
#pragma unroll
        for (int t = 0; t < KS; ++t) {
            e[t] = expf(kv[r][lane * KS + t] - mx);
            sum += e[t];
        }
        float inv = 1.f / sum;
#pragma unroll
        for (int t = 0; t < KS; ++t)
            kern_sm[((size_t)row * HEADS + lane) * KS + t] = e[t] * inv;
    }
}

// ---------------- conv_out: register sliding window (8 positions/thread) ----------------
__global__ __launch_bounds__(256) void convout_kernel(const float* __restrict__ co,
                                                      const float* __restrict__ kern_sm,
                                                      float* __restrict__ out) {
    const int t = threadIdx.x;
    const int c4l = t & 31;                  // 32 consecutive c4 -> 512B coalesced rows
    const int sg = t >> 5;                   // 0..7
    const int c4 = blockIdx.x * 32 + c4l;    // 0..95
    const int s0 = (blockIdx.y * 8 + sg) * 8;
    const int b = blockIdx.z;
    const int c = c4 * 4;
    const int h = c >> 6;

    const float* base = co + (size_t)b * SEQ * ALLH + c;
    float* obase = out + (size_t)b * SEQ * (2 * ALLH) + ALLH + c;
    const float* kbase = kern_sm + ((size_t)b * SEQ) * (HEADS * KS) + h * KS;

    float4 win[KS];
#pragma unroll
    for (int tt = 0; tt < KS; ++tt) {
        int sj = s0 - PADC + tt;
        win[tt] = (sj >= 0 && sj < SEQ) ? *reinterpret_cast<const float4*>(base + (size_t)sj * ALLH)
                                        : float4{0.f, 0.f, 0.f, 0.f};
    }

#pragma unroll
    for (int i = 0; i < 8; ++i) {
        const int s = s0 + i;
        const float* kr = kbase + (size_t)s * (HEADS * KS);
        float4 acc = {0.f, 0.f, 0.f, 0.f};
#pragma unroll
        for (int tt = 0; tt < KS; ++tt) {
            const float kt = kr[tt];
            acc.x += win[tt].x * kt;
            acc.y += win[tt].y * kt;
            acc.z += win[tt].z * kt;
            acc.w += win[tt].w * kt;
        }
        *reinterpret_cast<float4*>(obase + (size_t)s * (2 * ALLH)) = acc;
#pragma unroll
        for (int tt = 0; tt < KS - 1; ++tt) win[tt] = win[tt + 1];
        int sj = s + 1 + PADC;
        win[KS - 1] = (sj < SEQ) ? *reinterpret_cast<const float4*>(base + (size_t)sj * ALLH)
                                 : float4{0.f, 0.f, 0.f, 0.f};
    }
}

// ---------------- fused monotonic attention (MFMA, pre-swizzled tiles; verbatim R10/R12/R13) ----------------
__global__ __launch_bounds__(256) void attn_mfma(const ushort* __restrict__ qh,
                                                 const ushort* __restrict__ kh,
                                                 const ushort* __restrict__ vh,
                                                 const int* __restrict__ mask,
                                                 const float* __restrict__ gammas,
                                                 float* __restrict__ out) {
    __shared__ __align__(16) ushort kbuf[64 * 64];   // swizzled [key][d] tile (copied verbatim)
    __shared__ __align__(16) ushort vbuf[64 * 64];   // transposed+swizzled [d][key] tile
    __shared__ float s_msk[SEQ];

    const int bid = blockIdx.x;
    const int blk = (bid & 7) * 96 + (bid >> 3);
    const int qt = blk & 15;
    const int h = (blk >> 4) % HEADS;
    const int b = blk / (16 * HEADS);
    const int i0 = qt * 64;
    const int tid = threadIdx.x;
    const int lane = tid & 63;
    const int w = tid >> 6;
    const int g = lane >> 4;
    const int c = lane & 15;

    const float LOG2E = 1.44269504f;
    float g0 = gammas[h];
    float gamma2 = -(fmaxf(g0, 0.f) + log1pf(expf(-fabsf(g0)))) * LOG2E;  // -softplus * log2e
    const float SLOG2 = 0.125f * LOG2E;

    const ushort* ktiles = kh + ((size_t)(b * HEADS + h) * 16) * 4096;
    const ushort* vtiles = vh + ((size_t)(b * HEADS + h) * 16) * 4096;
    const ushort* qhb = qh + ((size_t)b * HEADS + h) * SEQ * 64;

    for (int e = tid; e < SEQ; e += 256)
        s_msk[e] = (mask[b * SEQ + e] != 0) ? 1.f : 0.f;

    // Q B-fragments
    bf16x8 qf0, qf1;
    {
        const ushort* qrow = qhb + (size_t)(i0 + w * 16 + c) * 64 + g * 8;
        qf0 = *reinterpret_cast<const bf16x8*>(qrow);
        qf1 = *reinterpret_cast<const bf16x8*>(qrow + 32);
    }

    // ================= pass 1: raw denominator T =================
    float Tacc = 0.f;
    for (int chk = 0; chk < 16; ++chk) {
        __syncthreads();
        const ushort* ktp = ktiles + chk * 4096;
#pragma unroll
        for (int it = 0; it < 2; ++it) {
            int e16 = (tid + it * 256) * 16;
            *reinterpret_cast<uint4*>((char*)kbuf + e16) =
                *reinterpret_cast<const uint4*>((const char*)ktp + e16);
        }
        __syncthreads();
        const int j0 = chk * 64;
#pragma unroll
        for (int m = 0; m < 4; ++m) {
            f32x4 acc = {0.f, 0.f, 0.f, 0.f};
            int row = m * 16 + c;
            int sw = (row & 7) << 4;
            bf16x8 kf0 = *reinterpret_cast<const bf16x8*>((char*)kbuf + row * 128 + ((g * 16) ^ sw));
            bf16x8 kf1 = *reinterpret_cast<const bf16x8*>((char*)kbuf + row * 128 + ((64 + g * 16) ^ sw));
            acc = __builtin_amdgcn_mfma_f32_16x16x32_bf16(kf0, qf0, acc, 0, 0, 0);
            acc = __builtin_amdgcn_mfma_f32_16x16x32_bf16(kf1, qf1, acc, 0, 0, 0);
#pragma unroll
            for (int r = 0; r < 4; ++r) {
                float mk = s_msk[j0 + m * 16 + g * 4 + r];
                Tacc += mk * fexp2(acc[r] * SLOG2);
            }
        }
    }
    Tacc += __shfl_xor(Tacc, 16, 64);
    Tacc += __shfl_xor(Tacc, 32, 64);
    const float T = Tacc;
    const float invT = (T > 0.f) ? 1.f / T : 0.f;

    // ================= pass 2: cum, effect, second softmax, PV =================
    f32x4 ctx0 = {0,0,0,0}, ctx1 = {0,0,0,0}, ctx2 = {0,0,0,0}, ctx3 = {0,0,0,0};
    float l2acc = 0.f;
    float base = 0.f;
    const float iq = (float)(i0 + w * 16 + c);
    const unsigned vx = (unsigned)((c & 7) << 4);    // lane-const read swizzle

    for (int chk = 0; chk < 16; ++chk) {
        __syncthreads();
        const ushort* ktp = ktiles + chk * 4096;
        const ushort* vtp = vtiles + chk * 4096;
#pragma unroll
        for (int it = 0; it < 2; ++it) {
            int e16 = (tid + it * 256) * 16;
            *reinterpret_cast<uint4*>((char*)kbuf + e16) =
                *reinterpret_cast<const uint4*>((const char*)ktp + e16);
            *reinterpret_cast<uint4*>((char*)vbuf + e16) =
                *reinterpret_cast<const uint4*>((const char*)vtp + e16);
        }
        __syncthreads();
        const int j0 = chk * 64;
#pragma unroll
        for (int m = 0; m < 4; ++m) {
            f32x4 acc = {0.f, 0.f, 0.f, 0.f};
            int row = m * 16 + c;
            int sw = (row & 7) << 4;
            bf16x8 kf0 = *reinterpret_cast<const bf16x8*>((char*)kbuf + row * 128 + ((g * 16) ^ sw));
            bf16x8 kf1 = *reinterpret_cast<const bf16x8*>((char*)kbuf + row * 128 + ((64 + g * 16) ^ sw));
            acc = __builtin_amdgcn_mfma_f32_16x16x32_bf16(kf0, qf0, acc, 0, 0, 0);
            acc = __builtin_amdgcn_mfma_f32_16x16x32_bf16(kf1, qf1, acc, 0, 0, 0);

            float sl[4], mk[4], incl[4];
            float li = 0.f;
#pragma unroll
            for (int r = 0; r < 4; ++r) {
                mk[r] = s_msk[j0 + m * 16 + g * 4 + r];
                sl[r] = acc[r] * SLOG2;                 // score in log2 units
                float e = mk[r] * fexp2(sl[r]);
                li += e;
                incl[r] = li;
            }
            float gs = li;
            float up = __shfl_up(gs, 16, 64); if (g >= 1) gs += up;
            up = __shfl_up(gs, 32, 64); if (g >= 2) gs += up;
            float gexcl = gs - li;
            float ttot = __shfl(gs, 48 + c, 64);

            const float dbase = iq - (float)(j0 + m * 16 + g * 4);
            float p2[4];
#pragma unroll
            for (int r = 0; r < 4; ++r) {
                float cum = base + gexcl + incl[r];
                float rem = fmaxf(1.0f - cum * invT, 0.f);
                float pos = fabsf(dbase - (float)r);
                float dist = fsqrt(rem * pos);
                float eff = fmaxf(fexp2(dist * gamma2), 1e-5f);  // gamma2<0, dist>=0 -> eff<=1
                p2[r] = mk[r] * fexp2(sl[r] * eff);
                l2acc += p2[r];
            }
            base += ttot;

            union { uint2 u; bf16x4 v; } pu;
            pu.u.x = cvtpk(p2[0], p2[1]);
            pu.u.y = cvtpk(p2[2], p2[3]);
            bf16x4 pa = pu.v;

            const unsigned cb = ((unsigned)(32 * m + 8 * g)) ^ vx;
#pragma unroll
            for (int t = 0; t < 4; ++t) {
                bf16x4 vfrag = *reinterpret_cast<const bf16x4*>((char*)vbuf + (unsigned)(c + 16 * t) * 128 + cb);
                if (t == 0) mfma16(ctx0, pa, vfrag);
                else if (t == 1) mfma16(ctx1, pa, vfrag);
                else if (t == 2) mfma16(ctx2, pa, vfrag);
                else mfma16(ctx3, pa, vfrag);
            }
        }
    }
    l2acc += __shfl_xor(l2acc, 16, 64);
    l2acc += __shfl_xor(l2acc, 32, 64);
    const float invl2 = 1.f / l2acc;

#pragma unroll
    for (int r = 0; r < 4; ++r) {
        float inv_r = __shfl(invl2, g * 4 + r, 64);
        int qrow = i0 + w * 16 + g * 4 + r;
        float* orow = out + ((size_t)b * SEQ + qrow) * (2 * ALLH) + h * DHEAD;
        orow[c +  0] = ctx0[r] * inv_r;
        orow[c + 16] = ctx1[r] * inv_r;
        orow[c + 32] = ctx2[r] * inv_r;
        orow[c + 48] = ctx3[r] * inv_r;
    }
}

// ---------------- launch ----------------
extern "C" void kernel_launch(void* const* d_in, const int* in_sizes, int n_in,
                              void* d_out, int out_size, void* d_ws, size_t ws_size,
                              hipStream_t stream) {
    const float* Q = (const float*)d_in[0];
    const float* Kin = (const float*)d_in[1];
    const float* V = (const float*)d_in[2];
    const float* Wq = (const float*)d_in[3];
    const float* Wk = (const float*)d_in[4];
    const float* Wv = (const float*)d_in[5];
    const float* dw = (const float*)d_in[6];
    const float* pw = (const float*)d_in[7];
    const float* sep_bias = (const float*)d_in[8];
    const float* Wck = (const float*)d_in[9];
    const float* bck = (const float*)d_in[10];
    const float* Wco = (const float*)d_in[11];
    const float* bco = (const float*)d_in[12];
    const float* gammas = (const float*)d_in[13];
    const int* mask = (const int*)d_in[14];
    float* out = (float*)d_out;
    float* ws = (float*)d_ws;

    const size_t NP = (size_t)MROWS * ALLH;        // 3145728
    const size_t WSZ = (size_t)ALLH * HID;         // 294912
    float* qb   = ws;                              // f32 q (spankern)
    float* cob  = qb + NP;
    float* kcb  = cob + NP;
    float* kern = kcb + NP;                        // 8192*54
    ushort* qh  = (ushort*)(kern + (size_t)MROWS * HEADS * KS);
    ushort* khm = qh + NP;                         // swizzled K tiles
    ushort* vhm = khm + NP;                        // transposed+swizzled V tiles
    ushort* ybf = vhm + NP;                        // dconv out bf16 [8192][768]
    ushort* WqT = ybf + (size_t)MROWS * HID;
    ushort* WkT = WqT + WSZ;
    ushort* WvT = WkT + WSZ;
    ushort* WcoT = WvT + WSZ;
    ushort* pwT = WcoT + WSZ;

    // 1. depthwise conv (register sliding window) + weight conversions
    dconv_kernel<<<dim3(3, 16, BATCH), 256, 0, stream>>>(Kin, dw, ybf);
    wcvt_kernel<<<dim3(24, 12, 4), 256, 0, stream>>>(Wq, Wk, Wv, Wco, WqT, WkT, WvT, WcoT);
    pwcvt_kernel<<<(ALLH * HID + 255) / 256, 256, 0, stream>>>(pw, pwT);

    // 2. all five projection GEMMs in one 128x128-tile dispatch (R14-proven)
    gemm_all<<<960, 256, 0, stream>>>(Q, Kin, V, ybf, WqT, WkT, WvT, WcoT, pwT,
                                      bco, sep_bias, qb, qh, khm, vhm, cob, kcb);

    // 3. span-dynamic-conv kernel weights + softmax
    spankern_kernel<<<MROWS / 4, 256, 0, stream>>>(kcb, qb, Wck, bck, kern);

    // 4. conv branch output (channels 384..767), register sliding window
    convout_kernel<<<dim3(3, 16, BATCH), 256, 0, stream>>>(cob, kern, out);

    // 5. fused monotonic attention (channels 0..383)
    attn_mfma<<<BATCH * HEADS * (SEQ / 64), 256, 0, stream>>>(qh, khm, vhm, mask, gammas, out);
}

// Round 18
// 190.966 us; speedup vs baseline: 2.7565x; 1.1691x over previous
//
#include <hip/hip_runtime.h>
#include <math.h>

#define BATCH 8
#define SEQ   1024
#define HID   768
#define HEADS 6
#define DHEAD 64
#define ALLH  384   // HEADS*DHEAD
#define KS    9
#define PADC  4
#define MROWS (BATCH*SEQ)  // 8192

typedef __attribute__((ext_vector_type(8))) short bf16x8;
typedef __attribute__((ext_vector_type(4))) short bf16x4;
typedef __attribute__((ext_vector_type(4))) float f32x4;

__device__ __forceinline__ ushort f2bf(float x) {   // RTN-even f32 -> bf16 bits
    unsigned u = __float_as_uint(x);
    unsigned r = (u + 0x7FFFu + ((u >> 16) & 1u)) >> 16;
    return (ushort)r;
}
__device__ __forceinline__ unsigned pk2(float a, float b) {
    return (unsigned)f2bf(a) | ((unsigned)f2bf(b) << 16);
}
// TRANS ops via compiler-known paths (hazard handling) -- R7 lesson
__device__ __forceinline__ float fexp2(float x) {
#if __has_builtin(__builtin_amdgcn_exp2f)
    return __builtin_amdgcn_exp2f(x);
#else
    return exp2f(x);
#endif
}
__device__ __forceinline__ float fsqrt(float x) {
#if __has_builtin(__builtin_amdgcn_sqrtf)
    return __builtin_amdgcn_sqrtf(x);
#else
    return __sqrtf(x);
#endif
}
__device__ __forceinline__ unsigned cvtpk(float a, float b) {  // 2 bf16 in 1 instr (RNE, non-trans)
    unsigned r; asm("v_cvt_pk_bf16_f32 %0, %1, %2" : "=v"(r) : "v"(a), "v"(b)); return r;
}

__device__ __forceinline__ void mfma16(f32x4& c4, bf16x4 a, bf16x4 b) {
#if __has_builtin(__builtin_amdgcn_mfma_f32_16x16x16bf16_1k)
    c4 = __builtin_amdgcn_mfma_f32_16x16x16bf16_1k(a, b, c4, 0, 0, 0);
#else
    asm volatile("v_mfma_f32_16x16x16_bf16 %0, %1, %2, %0" : "+v"(c4) : "v"(a), "v"(b));
#endif
}

// ---------------- depthwise conv on K -> bf16, register sliding window ----------------
__global__ __launch_bounds__(256) void dconv_kernel(const float* __restrict__ Kin,
                                                    const float* __restrict__ dw,
                                                    ushort* __restrict__ y) {
    const int t = threadIdx.x;
    const int c4l = t & 63;
    const int sg = t >> 6;
    const int c4 = blockIdx.x * 64 + c4l;
    const int s0 = blockIdx.y * 64 + sg * 16;
    const int b = blockIdx.z;
    const int c = c4 * 4;

    const float* base = Kin + (size_t)b * SEQ * HID + c;
    ushort* ybase = y + (size_t)b * SEQ * HID + c;

    float wv[4][KS];
#pragma unroll
    for (int j = 0; j < 4; ++j)
#pragma unroll
        for (int tt = 0; tt < KS; ++tt) wv[j][tt] = dw[(c + j) * KS + tt];

    float4 win[KS];
#pragma unroll
    for (int tt = 0; tt < KS; ++tt) {
        int sj = s0 - PADC + tt;
        win[tt] = (sj >= 0 && sj < SEQ) ? *reinterpret_cast<const float4*>(base + (size_t)sj * HID)
                                        : float4{0.f, 0.f, 0.f, 0.f};
    }

#pragma unroll
    for (int i = 0; i < 16; ++i) {
        const int s = s0 + i;
        float4 acc = {0.f, 0.f, 0.f, 0.f};
#pragma unroll
        for (int tt = 0; tt < KS; ++tt) {
            acc.x += win[tt].x * wv[0][tt];
            acc.y += win[tt].y * wv[1][tt];
            acc.z += win[tt].z * wv[2][tt];
            acc.w += win[tt].w * wv[3][tt];
        }
        uint2 o;
        o.x = pk2(acc.x, acc.y); o.y = pk2(acc.z, acc.w);
        *reinterpret_cast<uint2*>(ybase + (size_t)s * HID) = o;
#pragma unroll
        for (int tt = 0; tt < KS - 1; ++tt) win[tt] = win[tt + 1];
        int sj = s + 1 + PADC;
        win[KS - 1] = (sj < SEQ) ? *reinterpret_cast<const float4*>(base + (size_t)sj * HID)
                                 : float4{0.f, 0.f, 0.f, 0.f};
    }
}

// ---------------- weight transpose-convert: W[768,384] f32 -> Wt[384,768] bf16 ----------------
__global__ __launch_bounds__(256) void wcvt_kernel(const float* __restrict__ W0, const float* __restrict__ W1,
                                                   const float* __restrict__ W2, const float* __restrict__ W3,
                                                   ushort* __restrict__ O0, ushort* __restrict__ O1,
                                                   ushort* __restrict__ O2, ushort* __restrict__ O3) {
    __shared__ float t[32][33];
    int wsel = blockIdx.z;
    const float* W = wsel == 0 ? W0 : wsel == 1 ? W1 : wsel == 2 ? W2 : W3;
    ushort* O = wsel == 0 ? O0 : wsel == 1 ? O1 : wsel == 2 ? O2 : O3;
    int kt = blockIdx.x * 32;
    int nt = blockIdx.y * 32;
    int tx = threadIdx.x & 31, ty = threadIdx.x >> 5;
#pragma unroll
    for (int i = 0; i < 4; ++i)
        t[ty + i * 8][tx] = W[(size_t)(kt + ty + i * 8) * ALLH + nt + tx];
    __syncthreads();
#pragma unroll
    for (int i = 0; i < 4; ++i)
        O[(size_t)(nt + ty + i * 8) * HID + kt + tx] = f2bf(t[tx][ty + i * 8]);
}

// ---------------- pw convert (already [N=384, K=768]) ----------------
__global__ __launch_bounds__(256) void pwcvt_kernel(const float* __restrict__ pw, ushort* __restrict__ pwb) {
    int i = blockIdx.x * 256 + threadIdx.x;
    if (i < ALLH * HID) pwb[i] = f2bf(pw[i]);
}

// ---------------- merged projection GEMMs, 128x128 tiles, 8 waves (occupancy lever) ----------------
// 5 units x 192 blocks = 960. unit: 0=Q->qb+qh, 1=K->khm tiles, 2=V@Wv->vhm tiles,
// 3=V@Wco->cob(+bco), 4=ybf@pw->kcb(+sep_bias).
// Wave w (0..7) -> 32x64 sub-tile: wr = w>>1 (m 32-block), wc = w&1 (n 64-half).
// acc[2][4] = 32 AGPR; total regs < 128 -> 4 waves/SIMD.
__global__ __launch_bounds__(512) void gemm_all(const float* __restrict__ Q,
                                                const float* __restrict__ Kin,
                                                const float* __restrict__ V,
                                                const ushort* __restrict__ ybf,
                                                const ushort* __restrict__ WqT,
                                                const ushort* __restrict__ WkT,
                                                const ushort* __restrict__ WvT,
                                                const ushort* __restrict__ WcoT,
                                                const ushort* __restrict__ pwT,
                                                const float* __restrict__ bco,
                                                const float* __restrict__ sep_bias,
                                                float* __restrict__ qb,
                                                ushort* __restrict__ qh,
                                                ushort* __restrict__ khm,
                                                ushort* __restrict__ vhm,
                                                float* __restrict__ cob,
                                                float* __restrict__ kcb) {
    __shared__ __align__(16) ushort As[128 * 64];
    __shared__ __align__(16) ushort Bs[128 * 64];

    const int bx = blockIdx.x;
    const int swz = (bx & 7) * 120 + (bx >> 3);   // bijective: 960 = 8*120
    const int unit = swz / 192;
    const int local = swz % 192;
    const int n0 = (local % 3) * 128;
    const int m0 = (local / 3) * 128;

    const float* Af = unit == 0 ? Q : unit == 1 ? Kin : V;   // units 0..3 f32
    const ushort* Ab = ybf;                                   // unit 4 bf16
    const ushort* Bt = unit == 0 ? WqT : unit == 1 ? WkT : unit == 2 ? WvT : unit == 3 ? WcoT : pwT;
    const bool af32 = (unit != 4);

    const int tid = threadIdx.x;
    const int lane = tid & 63;
    const int w = tid >> 6;         // 0..7
    const int wr = w >> 1;          // 0..3 -> m 32-block
    const int wc = w & 1;           // 0..1 -> n 64-half
    const int g = lane >> 4;
    const int c = lane & 15;

    f32x4 acc[2][4];
#pragma unroll
    for (int i = 0; i < 2; ++i)
#pragma unroll
        for (int j = 0; j < 4; ++j) acc[i][j] = f32x4{0.f, 0.f, 0.f, 0.f};

    for (int k0 = 0; k0 < HID; k0 += 64) {
        __syncthreads();
#pragma unroll
        for (int it = 0; it < 2; ++it) {
            int e = tid + it * 512;            // 0..1023
            int row = e >> 3;                  // 0..127
            int c8 = (e & 7) * 8;
            int boff = row * 128 + ((c8 * 2) ^ ((row & 7) << 4));
            if (af32) {
                const float4 f0 = *reinterpret_cast<const float4*>(&Af[(size_t)(m0 + row) * HID + k0 + c8]);
                const float4 f1 = *reinterpret_cast<const float4*>(&Af[(size_t)(m0 + row) * HID + k0 + c8 + 4]);
                uint4 p;
                p.x = pk2(f0.x, f0.y); p.y = pk2(f0.z, f0.w);
                p.z = pk2(f1.x, f1.y); p.w = pk2(f1.z, f1.w);
                *reinterpret_cast<uint4*>((char*)As + boff) = p;
            } else {
                const uint4 av = *reinterpret_cast<const uint4*>(&Ab[(size_t)(m0 + row) * HID + k0 + c8]);
                *reinterpret_cast<uint4*>((char*)As + boff) = av;
            }
            const uint4 bv = *reinterpret_cast<const uint4*>(&Bt[(size_t)(n0 + row) * HID + k0 + c8]);
            *reinterpret_cast<uint4*>((char*)Bs + boff) = bv;
        }
        __syncthreads();

        bf16x8 af0[2], af1[2];
#pragma unroll
        for (int mq = 0; mq < 2; ++mq) {
            const int arow = wr * 32 + mq * 16 + c;
            const int asw = (arow & 7) << 4;
            af0[mq] = *reinterpret_cast<const bf16x8*>((char*)As + arow * 128 + ((g * 16) ^ asw));
            af1[mq] = *reinterpret_cast<const bf16x8*>((char*)As + arow * 128 + ((64 + g * 16) ^ asw));
        }
#pragma unroll
        for (int nq = 0; nq < 4; ++nq) {
            const int brow = wc * 64 + nq * 16 + c;
            const int bsw = (brow & 7) << 4;
            bf16x8 bf0 = *reinterpret_cast<const bf16x8*>((char*)Bs + brow * 128 + ((g * 16) ^ bsw));
            bf16x8 bf1 = *reinterpret_cast<const bf16x8*>((char*)Bs + brow * 128 + ((64 + g * 16) ^ bsw));
#pragma unroll
            for (int mq = 0; mq < 2; ++mq) {
                acc[mq][nq] = __builtin_amdgcn_mfma_f32_16x16x32_bf16(af0[mq], bf0, acc[mq][nq], 0, 0, 0);
                acc[mq][nq] = __builtin_amdgcn_mfma_f32_16x16x32_bf16(af1[mq], bf1, acc[mq][nq], 0, 0, 0);
            }
        }
    }

    // ---------------- epilogues (R17 formulas, m-base = m0 + wr*32) ----------------
    if (unit == 2) {
        // V@Wv -> transposed+swizzled 64x64 tiles [d-row][key-col]
#pragma unroll
        for (int mq = 0; mq < 2; ++mq) {
            const int mbase = m0 + wr * 32 + mq * 16 + g * 4;   // key of acc[mq][nq][0]
            const int bb = mbase >> 10;
            const int st = (mbase & 1023) >> 6;
            const unsigned colb = (unsigned)(2 * (mbase & 63));  // 2*(key&63)
#pragma unroll
            for (int nq = 0; nq < 4; ++nq) {
                const int n = n0 + wc * 64 + nq * 16 + c;
                const int head = n >> 6;
                const int d = n & 63;
                char* tb = (char*)vhm + (((size_t)(bb * HEADS + head) * 16 + st) * 4096) * 2;
                unsigned off = (unsigned)d * 128 + (colb ^ ((d & 7) << 4));
                uint2 vv;
                vv.x = pk2(acc[mq][nq][0], acc[mq][nq][1]);
                vv.y = pk2(acc[mq][nq][2], acc[mq][nq][3]);
                *reinterpret_cast<uint2*>(tb + off) = vv;
            }
        }
        return;
    }

#pragma unroll
    for (int nq = 0; nq < 4; ++nq) {
        const int n = n0 + wc * 64 + nq * 16 + c;
        float bv = 0.f;
        if (unit == 3) bv = bco[n];
        if (unit == 4) bv = sep_bias[n];
#pragma unroll
        for (int mq = 0; mq < 2; ++mq) {
#pragma unroll
            for (int r = 0; r < 4; ++r) {
                const int m = m0 + wr * 32 + mq * 16 + g * 4 + r;
                float v = acc[mq][nq][r] + bv;
                if (unit == 0) {
                    qb[(size_t)m * ALLH + n] = v;
                    int bb = m >> 10, s = m & 1023;
                    int head = n >> 6, d = n & 63;
                    qh[(((size_t)bb * HEADS + head) * SEQ + s) * 64 + d] = f2bf(v);
                } else if (unit == 1) {
                    int bb = m >> 10, s = m & 1023;
                    int head = n >> 6, d = n & 63;
                    char* tb = (char*)khm + (((size_t)(bb * HEADS + head) * 16 + (s >> 6)) * 4096) * 2;
                    unsigned off = (unsigned)(s & 63) * 128 + (((unsigned)(d * 2)) ^ ((s & 7) << 4));
                    *reinterpret_cast<ushort*>(tb + off) = f2bf(v);
                } else if (unit == 3) {
                    cob[(size_t)m * ALLH + n] = v;
                } else {  // unit 4
                    kcb[(size_t)m * ALLH + n] = v;
                }
            }
        }
    }
}

// ---------------- span kernel (float4 dot loop) ----------------
__global__ __launch_bounds__(256) void spankern_kernel(const float* __restrict__ keyconv,
                                                       const float* __restrict__ q,
                                                       const float* __restrict__ Wck,
                                                       const float* __restrict__ bck,
                                                       float* __restrict__ kern_sm) {
    __shared__ __align__(16) float ca[4][ALLH];
    __shared__ float kv[4][64];
    int row0 = blockIdx.x * 4;
    int tid = threadIdx.x;
    int r = tid >> 6;
    int lane = tid & 63;
    int row = row0 + r;
    for (int e = lane; e < ALLH / 4; e += 64) {
        size_t off = (size_t)row * ALLH + e * 4;
        const float4 kc = *reinterpret_cast<const float4*>(&keyconv[off]);
        const float4 qq = *reinterpret_cast<const float4*>(&q[off]);
        float4 p; p.x = kc.x * qq.x; p.y = kc.y * qq.y; p.z = kc.z * qq.z; p.w = kc.w * qq.w;
        *reinterpret_cast<float4*>(&ca[r][e * 4]) = p;
    }
    __syncthreads();
    float val = 0.f;
    if (lane < HEADS * KS) {
#pragma unroll 4
        for (int k4 = 0; k4 < ALLH / 4; ++k4) {
            const float4 cav = *reinterpret_cast<const float4*>(&ca[r][k4 * 4]);
            val += cav.x * Wck[(k4 * 4 + 0) * (HEADS * KS) + lane];
            val += cav.y * Wck[(k4 * 4 + 1) * (HEADS * KS) + lane];
            val += cav.z * Wck[(k4 * 4 + 2) * (HEADS * KS) + lane];
            val += cav.w * Wck[(k4 * 4 + 3) * (HEADS * KS) + lane];
        }
        val += bck[lane];
    }
    kv[r][lane] = val;
    __syncthreads();
    if (lane < HEADS) {
        float mx = -INFINITY;
#pragma unroll
        for (int t = 0; t < KS; ++t) mx = fmaxf(mx, kv[r][lane * KS + t]);
        float e[KS];
        float sum = 0.f;
#pragma unroll
        for (int t = 0; t < KS; ++t) {
            e[t] = expf(kv[r][lane * KS + t] - mx);
            sum += e[t];
        }
        float inv = 1.f / sum;
#pragma unroll
        for (int t = 0; t < KS; ++t)
            kern_sm[((size_t)row * HEADS + lane) * KS + t] = e[t] * inv;
    }
}

// ---------------- conv_out: register sliding window (8 positions/thread) ----------------
__global__ __launch_bounds__(256) void convout_kernel(const float* __restrict__ co,
                                                      const float* __restrict__ kern_sm,
                                                      float* __restrict__ out) {
    const int t = threadIdx.x;
    const int c4l = t & 31;                  // 32 consecutive c4 -> 512B coalesced rows
    const int sg = t >> 5;                   // 0..7
    const int c4 = blockIdx.x * 32 + c4l;    // 0..95
    const int s0 = (blockIdx.y * 8 + sg) * 8;
    const int b = blockIdx.z;
    const int c = c4 * 4;
    const int h = c >> 6;

    const float* base = co + (size_t)b * SEQ * ALLH + c;
    float* obase = out + (size_t)b * SEQ * (2 * ALLH) + ALLH + c;
    const float* kbase = kern_sm + ((size_t)b * SEQ) * (HEADS * KS) + h * KS;

    float4 win[KS];
#pragma unroll
    for (int tt = 0; tt < KS; ++tt) {
        int sj = s0 - PADC + tt;
        win[tt] = (sj >= 0 && sj < SEQ) ? *reinterpret_cast<const float4*>(base + (size_t)sj * ALLH)
                                        : float4{0.f, 0.f, 0.f, 0.f};
    }

#pragma unroll
    for (int i = 0; i < 8; ++i) {
        const int s = s0 + i;
        const float* kr = kbase + (size_t)s * (HEADS * KS);
        float4 acc = {0.f, 0.f, 0.f, 0.f};
#pragma unroll
        for (int tt = 0; tt < KS; ++tt) {
            const float kt = kr[tt];
            acc.x += win[tt].x * kt;
            acc.y += win[tt].y * kt;
            acc.z += win[tt].z * kt;
            acc.w += win[tt].w * kt;
        }
        *reinterpret_cast<float4*>(obase + (size_t)s * (2 * ALLH)) = acc;
#pragma unroll
        for (int tt = 0; tt < KS - 1; ++tt) win[tt] = win[tt + 1];
        int sj = s + 1 + PADC;
        win[KS - 1] = (sj < SEQ) ? *reinterpret_cast<const float4*>(base + (size_t)sj * ALLH)
                                 : float4{0.f, 0.f, 0.f, 0.f};
    }
}

// ---------------- fused monotonic attention (MFMA, pre-swizzled tiles; verbatim R10/R12/R13) ----------------
__global__ __launch_bounds__(256) void attn_mfma(const ushort* __restrict__ qh,
                                                 const ushort* __restrict__ kh,
                                                 const ushort* __restrict__ vh,
                                                 const int* __restrict__ mask,
                                                 const float* __restrict__ gammas,
                                                 float* __restrict__ out) {
    __shared__ __align__(16) ushort kbuf[64 * 64];   // swizzled [key][d] tile (copied verbatim)
    __shared__ __align__(16) ushort vbuf[64 * 64];   // transposed+swizzled [d][key] tile
    __shared__ float s_msk[SEQ];

    const int bid = blockIdx.x;
    const int blk = (bid & 7) * 96 + (bid >> 3);
    const int qt = blk & 15;
    const int h = (blk >> 4) % HEADS;
    const int b = blk / (16 * HEADS);
    const int i0 = qt * 64;
    const int tid = threadIdx.x;
    const int lane = tid & 63;
    const int w = tid >> 6;
    const int g = lane >> 4;
    const int c = lane & 15;

    const float LOG2E = 1.44269504f;
    float g0 = gammas[h];
    float gamma2 = -(fmaxf(g0, 0.f) + log1pf(expf(-fabsf(g0)))) * LOG2E;  // -softplus * log2e
    const float SLOG2 = 0.125f * LOG2E;

    const ushort* ktiles = kh + ((size_t)(b * HEADS + h) * 16) * 4096;
    const ushort* vtiles = vh + ((size_t)(b * HEADS + h) * 16) * 4096;
    const ushort* qhb = qh + ((size_t)b * HEADS + h) * SEQ * 64;

    for (int e = tid; e < SEQ; e += 256)
        s_msk[e] = (mask[b * SEQ + e] != 0) ? 1.f : 0.f;

    // Q B-fragments
    bf16x8 qf0, qf1;
    {
        const ushort* qrow = qhb + (size_t)(i0 + w * 16 + c) * 64 + g * 8;
        qf0 = *reinterpret_cast<const bf16x8*>(qrow);
        qf1 = *reinterpret_cast<const bf16x8*>(qrow + 32);
    }

    // ================= pass 1: raw denominator T =================
    float Tacc = 0.f;
    for (int chk = 0; chk < 16; ++chk) {
        __syncthreads();
        const ushort* ktp = ktiles + chk * 4096;
#pragma unroll
        for (int it = 0; it < 2; ++it) {
            int e16 = (tid + it * 256) * 16;
            *reinterpret_cast<uint4*>((char*)kbuf + e16) =
                *reinterpret_cast<const uint4*>((const char*)ktp + e16);
        }
        __syncthreads();
        const int j0 = chk * 64;
#pragma unroll
        for (int m = 0; m < 4; ++m) {
            f32x4 acc = {0.f, 0.f, 0.f, 0.f};
            int row = m * 16 + c;
            int sw = (row & 7) << 4;
            bf16x8 kf0 = *reinterpret_cast<const bf16x8*>((char*)kbuf + row * 128 + ((g * 16) ^ sw));
            bf16x8 kf1 = *reinterpret_cast<const bf16x8*>((char*)kbuf + row * 128 + ((64 + g * 16) ^ sw));
            acc = __builtin_amdgcn_mfma_f32_16x16x32_bf16(kf0, qf0, acc, 0, 0, 0);
            acc = __builtin_amdgcn_mfma_f32_16x16x32_bf16(kf1, qf1, acc, 0, 0, 0);
#pragma unroll
            for (int r = 0; r < 4; ++r) {
                float mk = s_msk[j0 + m * 16 + g * 4 + r];
                Tacc += mk * fexp2(acc[r] * SLOG2);
            }
        }
    }
    Tacc += __shfl_xor(Tacc, 16, 64);
    Tacc += __shfl_xor(Tacc, 32, 64);
    const float T = Tacc;
    const float invT = (T > 0.f) ? 1.f / T : 0.f;

    // ================= pass 2: cum, effect, second softmax, PV =================
    f32x4 ctx0 = {0,0,0,0}, ctx1 = {0,0,0,0}, ctx2 = {0,0,0,0}, ctx3 = {0,0,0,0};
    float l2acc = 0.f;
    float base = 0.f;
    const float iq = (float)(i0 + w * 16 + c);
    const unsigned vx = (unsigned)((c & 7) << 4);    // lane-const read swizzle

    for (int chk = 0; chk < 16; ++chk) {
        __syncthreads();
        const ushort* ktp = ktiles + chk * 4096;
        const ushort* vtp = vtiles + chk * 4096;
#pragma unroll
        for (int it = 0; it < 2; ++it) {
            int e16 = (tid + it * 256) * 16;
            *reinterpret_cast<uint4*>((char*)kbuf + e16) =
                *reinterpret_cast<const uint4*>((const char*)ktp + e16);
            *reinterpret_cast<uint4*>((char*)vbuf + e16) =
                *reinterpret_cast<const uint4*>((const char*)vtp + e16);
        }
        __syncthreads();
        const int j0 = chk * 64;
#pragma unroll
        for (int m = 0; m < 4; ++m) {
            f32x4 acc = {0.f, 0.f, 0.f, 0.f};
            int row = m * 16 + c;
            int sw = (row & 7) << 4;
            bf16x8 kf0 = *reinterpret_cast<const bf16x8*>((char*)kbuf + row * 128 + ((g * 16) ^ sw));
            bf16x8 kf1 = *reinterpret_cast<const bf16x8*>((char*)kbuf + row * 128 + ((64 + g * 16) ^ sw));
            acc = __builtin_amdgcn_mfma_f32_16x16x32_bf16(kf0, qf0, acc, 0, 0, 0);
            acc = __builtin_amdgcn_mfma_f32_16x16x32_bf16(kf1, qf1, acc, 0, 0, 0);

            float sl[4], mk[4], incl[4];
            float li = 0.f;
#pragma unroll
            for (int r = 0; r < 4; ++r) {
                mk[r] = s_msk[j0 + m * 16 + g * 4 + r];
                sl[r] = acc[r] * SLOG2;                 // score in log2 units
                float e = mk[r] * fexp2(sl[r]);
                li += e;
                incl[r] = li;
            }
            float gs = li;
            float up = __shfl_up(gs, 16, 64); if (g >= 1) gs += up;
            up = __shfl_up(gs, 32, 64); if (g >= 2) gs += up;
            float gexcl = gs - li;
            float ttot = __shfl(gs, 48 + c, 64);

            const float dbase = iq - (float)(j0 + m * 16 + g * 4);
            float p2[4];
#pragma unroll
            for (int r = 0; r < 4; ++r) {
                float cum = base + gexcl + incl[r];
                float rem = fmaxf(1.0f - cum * invT, 0.f);
                float pos = fabsf(dbase - (float)r);
                float dist = fsqrt(rem * pos);
                float eff = fmaxf(fexp2(dist * gamma2), 1e-5f);  // gamma2<0, dist>=0 -> eff<=1
                p2[r] = mk[r] * fexp2(sl[r] * eff);
                l2acc += p2[r];
            }
            base += ttot;

            union { uint2 u; bf16x4 v; } pu;
            pu.u.x = cvtpk(p2[0], p2[1]);
            pu.u.y = cvtpk(p2[2], p2[3]);
            bf16x4 pa = pu.v;

            const unsigned cb = ((unsigned)(32 * m + 8 * g)) ^ vx;
#pragma unroll
            for (int t = 0; t < 4; ++t) {
                bf16x4 vfrag = *reinterpret_cast<const bf16x4*>((char*)vbuf + (unsigned)(c + 16 * t) * 128 + cb);
                if (t == 0) mfma16(ctx0, pa, vfrag);
                else if (t == 1) mfma16(ctx1, pa, vfrag);
                else if (t == 2) mfma16(ctx2, pa, vfrag);
                else mfma16(ctx3, pa, vfrag);
            }
        }
    }
    l2acc += __shfl_xor(l2acc, 16, 64);
    l2acc += __shfl_xor(l2acc, 32, 64);
    const float invl2 = 1.f / l2acc;

#pragma unroll
    for (int r = 0; r < 4; ++r) {
        float inv_r = __shfl(invl2, g * 4 + r, 64);
        int qrow = i0 + w * 16 + g * 4 + r;
        float* orow = out + ((size_t)b * SEQ + qrow) * (2 * ALLH) + h * DHEAD;
        orow[c +  0] = ctx0[r] * inv_r;
        orow[c + 16] = ctx1[r] * inv_r;
        orow[c + 32] = ctx2[r] * inv_r;
        orow[c + 48] = ctx3[r] * inv_r;
    }
}

// ---------------- launch ----------------
extern "C" void kernel_launch(void* const* d_in, const int* in_sizes, int n_in,
                              void* d_out, int out_size, void* d_ws, size_t ws_size,
                              hipStream_t stream) {
    const float* Q = (const float*)d_in[0];
    const float* Kin = (const float*)d_in[1];
    const float* V = (const float*)d_in[2];
    const float* Wq = (const float*)d_in[3];
    const float* Wk = (const float*)d_in[4];
    const float* Wv = (const float*)d_in[5];
    const float* dw = (const float*)d_in[6];
    const float* pw = (const float*)d_in[7];
    const float* sep_bias = (const float*)d_in[8];
    const float* Wck = (const float*)d_in[9];
    const float* bck = (const float*)d_in[10];
    const float* Wco = (const float*)d_in[11];
    const float* bco = (const float*)d_in[12];
    const float* gammas = (const float*)d_in[13];
    const int* mask = (const int*)d_in[14];
    float* out = (float*)d_out;
    float* ws = (float*)d_ws;

    const size_t NP = (size_t)MROWS * ALLH;        // 3145728
    const size_t WSZ = (size_t)ALLH * HID;         // 294912
    float* qb   = ws;                              // f32 q (spankern)
    float* cob  = qb + NP;
    float* kcb  = cob + NP;
    float* kern = kcb + NP;                        // 8192*54
    ushort* qh  = (ushort*)(kern + (size_t)MROWS * HEADS * KS);
    ushort* khm = qh + NP;                         // swizzled K tiles
    ushort* vhm = khm + NP;                        // transposed+swizzled V tiles
    ushort* ybf = vhm + NP;                        // dconv out bf16 [8192][768]
    ushort* WqT = ybf + (size_t)MROWS * HID;
    ushort* WkT = WqT + WSZ;
    ushort* WvT = WkT + WSZ;
    ushort* WcoT = WvT + WSZ;
    ushort* pwT = WcoT + WSZ;

    // 1. depthwise conv (register sliding window) + weight conversions
    dconv_kernel<<<dim3(3, 16, BATCH), 256, 0, stream>>>(Kin, dw, ybf);
    wcvt_kernel<<<dim3(24, 12, 4), 256, 0, stream>>>(Wq, Wk, Wv, Wco, WqT, WkT, WvT, WcoT);
    pwcvt_kernel<<<(ALLH * HID + 255) / 256, 256, 0, stream>>>(pw, pwT);

    // 2. all five projection GEMMs, one 128x128-tile dispatch, 8 waves/block
    gemm_all<<<960, 512, 0, stream>>>(Q, Kin, V, ybf, WqT, WkT, WvT, WcoT, pwT,
                                      bco, sep_bias, qb, qh, khm, vhm, cob, kcb);

    // 3. span-dynamic-conv kernel weights + softmax
    spankern_kernel<<<MROWS / 4, 256, 0, stream>>>(kcb, qb, Wck, bck, kern);

    // 4. conv branch output (channels 384..767), register sliding window
    convout_kernel<<<dim3(3, 16, BATCH), 256, 0, stream>>>(cob, kern, out);

    // 5. fused monotonic attention (channels 0..383)
    attn_mfma<<<BATCH * HEADS * (SEQ / 64), 256, 0, stream>>>(qh, khm, vhm, mask, gammas, out);
}

// Round 19
// 190.842 us; speedup vs baseline: 2.7583x; 1.0007x over previous
//
#include <hip/hip_runtime.h>
#include <math.h>

#define BATCH 8
#define SEQ   1024
#define HID   768
#define HEADS 6
#define DHEAD 64
#define ALLH  384   // HEADS*DHEAD
#define KS    9
#define PADC  4
#define MROWS (BATCH*SEQ)  // 8192

typedef __attribute__((ext_vector_type(8))) short bf16x8;
typedef __attribute__((ext_vector_type(4))) short bf16x4;
typedef __attribute__((ext_vector_type(4))) float f32x4;

__device__ __forceinline__ ushort f2bf(float x) {   // RTN-even f32 -> bf16 bits
    unsigned u = __float_as_uint(x);
    unsigned r = (u + 0x7FFFu + ((u >> 16) & 1u)) >> 16;
    return (ushort)r;
}
__device__ __forceinline__ unsigned pk2(float a, float b) {
    return (unsigned)f2bf(a) | ((unsigned)f2bf(b) << 16);
}
// TRANS ops via compiler-known paths (hazard handling) -- R7 lesson
__device__ __forceinline__ float fexp2(float x) {
#if __has_builtin(__builtin_amdgcn_exp2f)
    return __builtin_amdgcn_exp2f(x);
#else
    return exp2f(x);
#endif
}
__device__ __forceinline__ float fsqrt(float x) {
#if __has_builtin(__builtin_amdgcn_sqrtf)
    return __builtin_amdgcn_sqrtf(x);
#else
    return __sqrtf(x);
#endif
}
__device__ __forceinline__ unsigned cvtpk(float a, float b) {  // 2 bf16 in 1 instr (RNE, non-trans)
    unsigned r; asm("v_cvt_pk_bf16_f32 %0, %1, %2" : "=v"(r) : "v"(a), "v"(b)); return r;
}

__device__ __forceinline__ void mfma16(f32x4& c4, bf16x4 a, bf16x4 b) {
#if __has_builtin(__builtin_amdgcn_mfma_f32_16x16x16bf16_1k)
    c4 = __builtin_amdgcn_mfma_f32_16x16x16bf16_1k(a, b, c4, 0, 0, 0);
#else
    asm volatile("v_mfma_f32_16x16x16_bf16 %0, %1, %2, %0" : "+v"(c4) : "v"(a), "v"(b));
#endif
}

// ---------------- depthwise conv on K -> bf16, register sliding window ----------------
__global__ __launch_bounds__(256) void dconv_kernel(const float* __restrict__ Kin,
                                                    const float* __restrict__ dw,
                                                    ushort* __restrict__ y) {
    const int t = threadIdx.x;
    const int c4l = t & 63;
    const int sg = t >> 6;
    const int c4 = blockIdx.x * 64 + c4l;
    const int s0 = blockIdx.y * 64 + sg * 16;
    const int b = blockIdx.z;
    const int c = c4 * 4;

    const float* base = Kin + (size_t)b * SEQ * HID + c;
    ushort* ybase = y + (size_t)b * SEQ * HID + c;

    float wv[4][KS];
#pragma unroll
    for (int j = 0; j < 4; ++j)
#pragma unroll
        for (int tt = 0; tt < KS; ++tt) wv[j][tt] = dw[(c + j) * KS + tt];

    float4 win[KS];
#pragma unroll
    for (int tt = 0; tt < KS; ++tt) {
        int sj = s0 - PADC + tt;
        win[tt] = (sj >= 0 && sj < SEQ) ? *reinterpret_cast<const float4*>(base + (size_t)sj * HID)
                                        : float4{0.f, 0.f, 0.f, 0.f};
    }

#pragma unroll
    for (int i = 0; i < 16; ++i) {
        const int s = s0 + i;
        float4 acc = {0.f, 0.f, 0.f, 0.f};
#pragma unroll
        for (int tt = 0; tt < KS; ++tt) {
            acc.x += win[tt].x * wv[0][tt];
            acc.y += win[tt].y * wv[1][tt];
            acc.z += win[tt].z * wv[2][tt];
            acc.w += win[tt].w * wv[3][tt];
        }
        uint2 o;
        o.x = pk2(acc.x, acc.y); o.y = pk2(acc.z, acc.w);
        *reinterpret_cast<uint2*>(ybase + (size_t)s * HID) = o;
#pragma unroll
        for (int tt = 0; tt < KS - 1; ++tt) win[tt] = win[tt + 1];
        int sj = s + 1 + PADC;
        win[KS - 1] = (sj < SEQ) ? *reinterpret_cast<const float4*>(base + (size_t)sj * HID)
                                 : float4{0.f, 0.f, 0.f, 0.f};
    }
}

// ---------------- weight transpose-convert: W[768,384] f32 -> Wt[384,768] bf16 ----------------
__global__ __launch_bounds__(256) void wcvt_kernel(const float* __restrict__ W0, const float* __restrict__ W1,
                                                   const float* __restrict__ W2, const float* __restrict__ W3,
                                                   ushort* __restrict__ O0, ushort* __restrict__ O1,
                                                   ushort* __restrict__ O2, ushort* __restrict__ O3) {
    __shared__ float t[32][33];
    int wsel = blockIdx.z;
    const float* W = wsel == 0 ? W0 : wsel == 1 ? W1 : wsel == 2 ? W2 : W3;
    ushort* O = wsel == 0 ? O0 : wsel == 1 ? O1 : wsel == 2 ? O2 : O3;
    int kt = blockIdx.x * 32;
    int nt = blockIdx.y * 32;
    int tx = threadIdx.x & 31, ty = threadIdx.x >> 5;
#pragma unroll
    for (int i = 0; i < 4; ++i)
        t[ty + i * 8][tx] = W[(size_t)(kt + ty + i * 8) * ALLH + nt + tx];
    __syncthreads();
#pragma unroll
    for (int i = 0; i < 4; ++i)
        O[(size_t)(nt + ty + i * 8) * HID + kt + tx] = f2bf(t[tx][ty + i * 8]);
}

// ---------------- pw convert (already [N=384, K=768]) ----------------
__global__ __launch_bounds__(256) void pwcvt_kernel(const float* __restrict__ pw, ushort* __restrict__ pwb) {
    int i = blockIdx.x * 256 + threadIdx.x;
    if (i < ALLH * HID) pwb[i] = f2bf(pw[i]);
}

// ---------------- merged projection GEMMs, 128x128 tiles, 8 waves (occupancy lever) ----------------
// 5 units x 192 blocks = 960. unit: 0=Q->qb+qh, 1=K->khm tiles, 2=V@Wv->vhm tiles,
// 3=V@Wco->cob(+bco), 4=ybf@pw->kcb(+sep_bias).
// Wave w (0..7) -> 32x64 sub-tile: wr = w>>1 (m 32-block), wc = w&1 (n 64-half).
// acc[2][4] = 32 AGPR; total regs < 128 -> 4 waves/SIMD.
__global__ __launch_bounds__(512) void gemm_all(const float* __restrict__ Q,
                                                const float* __restrict__ Kin,
                                                const float* __restrict__ V,
                                                const ushort* __restrict__ ybf,
                                                const ushort* __restrict__ WqT,
                                                const ushort* __restrict__ WkT,
                                                const ushort* __restrict__ WvT,
                                                const ushort* __restrict__ WcoT,
                                                const ushort* __restrict__ pwT,
                                                const float* __restrict__ bco,
                                                const float* __restrict__ sep_bias,
                                                float* __restrict__ qb,
                                                ushort* __restrict__ qh,
                                                ushort* __restrict__ khm,
                                                ushort* __restrict__ vhm,
                                                float* __restrict__ cob,
                                                float* __restrict__ kcb) {
    __shared__ __align__(16) ushort As[128 * 64];
    __shared__ __align__(16) ushort Bs[128 * 64];

    const int bx = blockIdx.x;
    const int swz = (bx & 7) * 120 + (bx >> 3);   // bijective: 960 = 8*120
    const int unit = swz / 192;
    const int local = swz % 192;
    const int n0 = (local % 3) * 128;
    const int m0 = (local / 3) * 128;

    const float* Af = unit == 0 ? Q : unit == 1 ? Kin : V;   // units 0..3 f32
    const ushort* Ab = ybf;                                   // unit 4 bf16
    const ushort* Bt = unit == 0 ? WqT : unit == 1 ? WkT : unit == 2 ? WvT : unit == 3 ? WcoT : pwT;
    const bool af32 = (unit != 4);

    const int tid = threadIdx.x;
    const int lane = tid & 63;
    const int w = tid >> 6;         // 0..7
    const int wr = w >> 1;          // 0..3 -> m 32-block
    const int wc = w & 1;           // 0..1 -> n 64-half
    const int g = lane >> 4;
    const int c = lane & 15;

    f32x4 acc[2][4];
#pragma unroll
    for (int i = 0; i < 2; ++i)
#pragma unroll
        for (int j = 0; j < 4; ++j) acc[i][j] = f32x4{0.f, 0.f, 0.f, 0.f};

    for (int k0 = 0; k0 < HID; k0 += 64) {
        __syncthreads();
#pragma unroll
        for (int it = 0; it < 2; ++it) {
            int e = tid + it * 512;            // 0..1023
            int row = e >> 3;                  // 0..127
            int c8 = (e & 7) * 8;
            int boff = row * 128 + ((c8 * 2) ^ ((row & 7) << 4));
            if (af32) {
                const float4 f0 = *reinterpret_cast<const float4*>(&Af[(size_t)(m0 + row) * HID + k0 + c8]);
                const float4 f1 = *reinterpret_cast<const float4*>(&Af[(size_t)(m0 + row) * HID + k0 + c8 + 4]);
                uint4 p;
                p.x = pk2(f0.x, f0.y); p.y = pk2(f0.z, f0.w);
                p.z = pk2(f1.x, f1.y); p.w = pk2(f1.z, f1.w);
                *reinterpret_cast<uint4*>((char*)As + boff) = p;
            } else {
                const uint4 av = *reinterpret_cast<const uint4*>(&Ab[(size_t)(m0 + row) * HID + k0 + c8]);
                *reinterpret_cast<uint4*>((char*)As + boff) = av;
            }
            const uint4 bv = *reinterpret_cast<const uint4*>(&Bt[(size_t)(n0 + row) * HID + k0 + c8]);
            *reinterpret_cast<uint4*>((char*)Bs + boff) = bv;
        }
        __syncthreads();

        bf16x8 af0[2], af1[2];
#pragma unroll
        for (int mq = 0; mq < 2; ++mq) {
            const int arow = wr * 32 + mq * 16 + c;
            const int asw = (arow & 7) << 4;
            af0[mq] = *reinterpret_cast<const bf16x8*>((char*)As + arow * 128 + ((g * 16) ^ asw));
            af1[mq] = *reinterpret_cast<const bf16x8*>((char*)As + arow * 128 + ((64 + g * 16) ^ asw));
        }
#pragma unroll
        for (int nq = 0; nq < 4; ++nq) {
            const int brow = wc * 64 + nq * 16 + c;
            const int bsw = (brow & 7) << 4;
            bf16x8 bf0 = *reinterpret_cast<const bf16x8*>((char*)Bs + brow * 128 + ((g * 16) ^ bsw));
            bf16x8 bf1 = *reinterpret_cast<const bf16x8*>((char*)Bs + brow * 128 + ((64 + g * 16) ^ bsw));
#pragma unroll
            for (int mq = 0; mq < 2; ++mq) {
                acc[mq][nq] = __builtin_amdgcn_mfma_f32_16x16x32_bf16(af0[mq], bf0, acc[mq][nq], 0, 0, 0);
                acc[mq][nq] = __builtin_amdgcn_mfma_f32_16x16x32_bf16(af1[mq], bf1, acc[mq][nq], 0, 0, 0);
            }
        }
    }

    // ---------------- epilogues (R17 formulas, m-base = m0 + wr*32) ----------------
    if (unit == 2) {
        // V@Wv -> transposed+swizzled 64x64 tiles [d-row][key-col]
#pragma unroll
        for (int mq = 0; mq < 2; ++mq) {
            const int mbase = m0 + wr * 32 + mq * 16 + g * 4;   // key of acc[mq][nq][0]
            const int bb = mbase >> 10;
            const int st = (mbase & 1023) >> 6;
            const unsigned colb = (unsigned)(2 * (mbase & 63));  // 2*(key&63)
#pragma unroll
            for (int nq = 0; nq < 4; ++nq) {
                const int n = n0 + wc * 64 + nq * 16 + c;
                const int head = n >> 6;
                const int d = n & 63;
                char* tb = (char*)vhm + (((size_t)(bb * HEADS + head) * 16 + st) * 4096) * 2;
                unsigned off = (unsigned)d * 128 + (colb ^ ((d & 7) << 4));
                uint2 vv;
                vv.x = pk2(acc[mq][nq][0], acc[mq][nq][1]);
                vv.y = pk2(acc[mq][nq][2], acc[mq][nq][3]);
                *reinterpret_cast<uint2*>(tb + off) = vv;
            }
        }
        return;
    }

#pragma unroll
    for (int nq = 0; nq < 4; ++nq) {
        const int n = n0 + wc * 64 + nq * 16 + c;
        float bv = 0.f;
        if (unit == 3) bv = bco[n];
        if (unit == 4) bv = sep_bias[n];
#pragma unroll
        for (int mq = 0; mq < 2; ++mq) {
#pragma unroll
            for (int r = 0; r < 4; ++r) {
                const int m = m0 + wr * 32 + mq * 16 + g * 4 + r;
                float v = acc[mq][nq][r] + bv;
                if (unit == 0) {
                    qb[(size_t)m * ALLH + n] = v;
                    int bb = m >> 10, s = m & 1023;
                    int head = n >> 6, d = n & 63;
                    qh[(((size_t)bb * HEADS + head) * SEQ + s) * 64 + d] = f2bf(v);
                } else if (unit == 1) {
                    int bb = m >> 10, s = m & 1023;
                    int head = n >> 6, d = n & 63;
                    char* tb = (char*)khm + (((size_t)(bb * HEADS + head) * 16 + (s >> 6)) * 4096) * 2;
                    unsigned off = (unsigned)(s & 63) * 128 + (((unsigned)(d * 2)) ^ ((s & 7) << 4));
                    *reinterpret_cast<ushort*>(tb + off) = f2bf(v);
                } else if (unit == 3) {
                    cob[(size_t)m * ALLH + n] = v;
                } else {  // unit 4
                    kcb[(size_t)m * ALLH + n] = v;
                }
            }
        }
    }
}

// ---------------- span kernel (float4 dot loop) ----------------
__global__ __launch_bounds__(256) void spankern_kernel(const float* __restrict__ keyconv,
                                                       const float* __restrict__ q,
                                                       const float* __restrict__ Wck,
                                                       const float* __restrict__ bck,
                                                       float* __restrict__ kern_sm) {
    __shared__ __align__(16) float ca[4][ALLH];
    __shared__ float kv[4][64];
    int row0 = blockIdx.x * 4;
    int tid = threadIdx.x;
    int r = tid >> 6;
    int lane = tid & 63;
    int row = row0 + r;
    for (int e = lane; e < ALLH / 4; e += 64) {
        size_t off = (size_t)row * ALLH + e * 4;
        const float4 kc = *reinterpret_cast<const float4*>(&keyconv[off]);
        const float4 qq = *reinterpret_cast<const float4*>(&q[off]);
        float4 p; p.x = kc.x * qq.x; p.y = kc.y * qq.y; p.z = kc.z * qq.z; p.w = kc.w * qq.w;
        *reinterpret_cast<float4*>(&ca[r][e * 4]) = p;
    }
    __syncthreads();
    float val = 0.f;
    if (lane < HEADS * KS) {
#pragma unroll 4
        for (int k4 = 0; k4 < ALLH / 4; ++k4) {
            const float4 cav = *reinterpret_cast<const float4*>(&ca[r][k4 * 4]);
            val += cav.x * Wck[(k4 * 4 + 0) * (HEADS * KS) + lane];
            val += cav.y * Wck[(k4 * 4 + 1) * (HEADS * KS) + lane];
            val += cav.z * Wck[(k4 * 4 + 2) * (HEADS * KS) + lane];
            val += cav.w * Wck[(k4 * 4 + 3) * (HEADS * KS) + lane];
        }
        val += bck[lane];
    }
    kv[r][lane] = val;
    __syncthreads();
    if (lane < HEADS) {
        float mx = -INFINITY;
#pragma unroll
        for (int t = 0; t < KS; ++t) mx = fmaxf(mx, kv[r][lane * KS + t]);
        float e[KS];
        float sum = 0.f;
#pragma unroll
        for (int t = 0; t < KS; ++t) {
            e[t] = expf(kv[r][lane * KS + t] - mx);
            sum += e[t];
        }
        float inv = 1.f / sum;
#pragma unroll
        for (int t = 0; t < KS; ++t)
            kern_sm[((size_t)row * HEADS + lane) * KS + t] = e[t] * inv;
    }
}

// ---------------- conv_out: register sliding window (8 positions/thread) ----------------
__global__ __launch_bounds__(256) void convout_kernel(const float* __restrict__ co,
                                                      const float* __restrict__ kern_sm,
                                                      float* __restrict__ out) {
    const int t = threadIdx.x;
    const int c4l = t & 31;                  // 32 consecutive c4 -> 512B coalesced rows
    const int sg = t >> 5;                   // 0..7
    const int c4 = blockIdx.x * 32 + c4l;    // 0..95
    const int s0 = (blockIdx.y * 8 + sg) * 8;
    const int b = blockIdx.z;
    const int c = c4 * 4;
    const int h = c >> 6;

    const float* base = co + (size_t)b * SEQ * ALLH + c;
    float* obase = out + (size_t)b * SEQ * (2 * ALLH) + ALLH + c;
    const float* kbase = kern_sm + ((size_t)b * SEQ) * (HEADS * KS) + h * KS;

    float4 win[KS];
#pragma unroll
    for (int tt = 0; tt < KS; ++tt) {
        int sj = s0 - PADC + tt;
        win[tt] = (sj >= 0 && sj < SEQ) ? *reinterpret_cast<const float4*>(base + (size_t)sj * ALLH)
                                        : float4{0.f, 0.f, 0.f, 0.f};
    }

#pragma unroll
    for (int i = 0; i < 8; ++i) {
        const int s = s0 + i;
        const float* kr = kbase + (size_t)s * (HEADS * KS);
        float4 acc = {0.f, 0.f, 0.f, 0.f};
#pragma unroll
        for (int tt = 0; tt < KS; ++tt) {
            const float kt = kr[tt];
            acc.x += win[tt].x * kt;
            acc.y += win[tt].y * kt;
            acc.z += win[tt].z * kt;
            acc.w += win[tt].w * kt;
        }
        *reinterpret_cast<float4*>(obase + (size_t)s * (2 * ALLH)) = acc;
#pragma unroll
        for (int tt = 0; tt < KS - 1; ++tt) win[tt] = win[tt + 1];
        int sj = s + 1 + PADC;
        win[KS - 1] = (sj < SEQ) ? *reinterpret_cast<const float4*>(base + (size_t)sj * ALLH)
                                 : float4{0.f, 0.f, 0.f, 0.f};
    }
}

// ---------------- fused monotonic attention (MFMA, pre-swizzled tiles; verbatim R10/R12/R13) ----------------
__global__ __launch_bounds__(256) void attn_mfma(const ushort* __restrict__ qh,
                                                 const ushort* __restrict__ kh,
                                                 const ushort* __restrict__ vh,
                                                 const int* __restrict__ mask,
                                                 const float* __restrict__ gammas,
                                                 float* __restrict__ out) {
    __shared__ __align__(16) ushort kbuf[64 * 64];   // swizzled [key][d] tile (copied verbatim)
    __shared__ __align__(16) ushort vbuf[64 * 64];   // transposed+swizzled [d][key] tile
    __shared__ float s_msk[SEQ];

    const int bid = blockIdx.x;
    const int blk = (bid & 7) * 96 + (bid >> 3);
    const int qt = blk & 15;
    const int h = (blk >> 4) % HEADS;
    const int b = blk / (16 * HEADS);
    const int i0 = qt * 64;
    const int tid = threadIdx.x;
    const int lane = tid & 63;
    const int w = tid >> 6;
    const int g = lane >> 4;
    const int c = lane & 15;

    const float LOG2E = 1.44269504f;
    float g0 = gammas[h];
    float gamma2 = -(fmaxf(g0, 0.f) + log1pf(expf(-fabsf(g0)))) * LOG2E;  // -softplus * log2e
    const float SLOG2 = 0.125f * LOG2E;

    const ushort* ktiles = kh + ((size_t)(b * HEADS + h) * 16) * 4096;
    const ushort* vtiles = vh + ((size_t)(b * HEADS + h) * 16) * 4096;
    const ushort* qhb = qh + ((size_t)b * HEADS + h) * SEQ * 64;

    for (int e = tid; e < SEQ; e += 256)
        s_msk[e] = (mask[b * SEQ + e] != 0) ? 1.f : 0.f;

    // Q B-fragments
    bf16x8 qf0, qf1;
    {
        const ushort* qrow = qhb + (size_t)(i0 + w * 16 + c) * 64 + g * 8;
        qf0 = *reinterpret_cast<const bf16x8*>(qrow);
        qf1 = *reinterpret_cast<const bf16x8*>(qrow + 32);
    }

    // ================= pass 1: raw denominator T =================
    float Tacc = 0.f;
    for (int chk = 0; chk < 16; ++chk) {
        __syncthreads();
        const ushort* ktp = ktiles + chk * 4096;
#pragma unroll
        for (int it = 0; it < 2; ++it) {
            int e16 = (tid + it * 256) * 16;
            *reinterpret_cast<uint4*>((char*)kbuf + e16) =
                *reinterpret_cast<const uint4*>((const char*)ktp + e16);
        }
        __syncthreads();
        const int j0 = chk * 64;
#pragma unroll
        for (int m = 0; m < 4; ++m) {
            f32x4 acc = {0.f, 0.f, 0.f, 0.f};
            int row = m * 16 + c;
            int sw = (row & 7) << 4;
            bf16x8 kf0 = *reinterpret_cast<const bf16x8*>((char*)kbuf + row * 128 + ((g * 16) ^ sw));
            bf16x8 kf1 = *reinterpret_cast<const bf16x8*>((char*)kbuf + row * 128 + ((64 + g * 16) ^ sw));
            acc = __builtin_amdgcn_mfma_f32_16x16x32_bf16(kf0, qf0, acc, 0, 0, 0);
            acc = __builtin_amdgcn_mfma_f32_16x16x32_bf16(kf1, qf1, acc, 0, 0, 0);
#pragma unroll
            for (int r = 0; r < 4; ++r) {
                float mk = s_msk[j0 + m * 16 + g * 4 + r];
                Tacc += mk * fexp2(acc[r] * SLOG2);
            }
        }
    }
    Tacc += __shfl_xor(Tacc, 16, 64);
    Tacc += __shfl_xor(Tacc, 32, 64);
    const float T = Tacc;
    const float invT = (T > 0.f) ? 1.f / T : 0.f;

    // ================= pass 2: cum, effect, second softmax, PV =================
    f32x4 ctx0 = {0,0,0,0}, ctx1 = {0,0,0,0}, ctx2 = {0,0,0,0}, ctx3 = {0,0,0,0};
    float l2acc = 0.f;
    float base = 0.f;
    const float iq = (float)(i0 + w * 16 + c);
    const unsigned vx = (unsigned)((c & 7) << 4);    // lane-const read swizzle

    for (int chk = 0; chk < 16; ++chk) {
        __syncthreads();
        const ushort* ktp = ktiles + chk * 4096;
        const ushort* vtp = vtiles + chk * 4096;
#pragma unroll
        for (int it = 0; it < 2; ++it) {
            int e16 = (tid + it * 256) * 16;
            *reinterpret_cast<uint4*>((char*)kbuf + e16) =
                *reinterpret_cast<const uint4*>((const char*)ktp + e16);
            *reinterpret_cast<uint4*>((char*)vbuf + e16) =
                *reinterpret_cast<const uint4*>((const char*)vtp + e16);
        }
        __syncthreads();
        const int j0 = chk * 64;
#pragma unroll
        for (int m = 0; m < 4; ++m) {
            f32x4 acc = {0.f, 0.f, 0.f, 0.f};
            int row = m * 16 + c;
            int sw = (row & 7) << 4;
            bf16x8 kf0 = *reinterpret_cast<const bf16x8*>((char*)kbuf + row * 128 + ((g * 16) ^ sw));
            bf16x8 kf1 = *reinterpret_cast<const bf16x8*>((char*)kbuf + row * 128 + ((64 + g * 16) ^ sw));
            acc = __builtin_amdgcn_mfma_f32_16x16x32_bf16(kf0, qf0, acc, 0, 0, 0);
            acc = __builtin_amdgcn_mfma_f32_16x16x32_bf16(kf1, qf1, acc, 0, 0, 0);

            float sl[4], mk[4], incl[4];
            float li = 0.f;
#pragma unroll
            for (int r = 0; r < 4; ++r) {
                mk[r] = s_msk[j0 + m * 16 + g * 4 + r];
                sl[r] = acc[r] * SLOG2;                 // score in log2 units
                float e = mk[r] * fexp2(sl[r]);
                li += e;
                incl[r] = li;
            }
            float gs = li;
            float up = __shfl_up(gs, 16, 64); if (g >= 1) gs += up;
            up = __shfl_up(gs, 32, 64); if (g >= 2) gs += up;
            float gexcl = gs - li;
            float ttot = __shfl(gs, 48 + c, 64);

            const float dbase = iq - (float)(j0 + m * 16 + g * 4);
            float p2[4];
#pragma unroll
            for (int r = 0; r < 4; ++r) {
                float cum = base + gexcl + incl[r];
                float rem = fmaxf(1.0f - cum * invT, 0.f);
                float pos = fabsf(dbase - (float)r);
                float dist = fsqrt(rem * pos);
                float eff = fmaxf(fexp2(dist * gamma2), 1e-5f);  // gamma2<0, dist>=0 -> eff<=1
                p2[r] = mk[r] * fexp2(sl[r] * eff);
                l2acc += p2[r];
            }
            base += ttot;

            union { uint2 u; bf16x4 v; } pu;
            pu.u.x = cvtpk(p2[0], p2[1]);
            pu.u.y = cvtpk(p2[2], p2[3]);
            bf16x4 pa = pu.v;

            const unsigned cb = ((unsigned)(32 * m + 8 * g)) ^ vx;
#pragma unroll
            for (int t = 0; t < 4; ++t) {
                bf16x4 vfrag = *reinterpret_cast<const bf16x4*>((char*)vbuf + (unsigned)(c + 16 * t) * 128 + cb);
                if (t == 0) mfma16(ctx0, pa, vfrag);
                else if (t == 1) mfma16(ctx1, pa, vfrag);
                else if (t == 2) mfma16(ctx2, pa, vfrag);
                else mfma16(ctx3, pa, vfrag);
            }
        }
    }
    l2acc += __shfl_xor(l2acc, 16, 64);
    l2acc += __shfl_xor(l2acc, 32, 64);
    const float invl2 = 1.f / l2acc;

#pragma unroll
    for (int r = 0; r < 4; ++r) {
        float inv_r = __shfl(invl2, g * 4 + r, 64);
        int qrow = i0 + w * 16 + g * 4 + r;
        float* orow = out + ((size_t)b * SEQ + qrow) * (2 * ALLH) + h * DHEAD;
        orow[c +  0] = ctx0[r] * inv_r;
        orow[c + 16] = ctx1[r] * inv_r;
        orow[c + 32] = ctx2[r] * inv_r;
        orow[c + 48] = ctx3[r] * inv_r;
    }
}

// ---------------- launch ----------------
extern "C" void kernel_launch(void* const* d_in, const int* in_sizes, int n_in,
                              void* d_out, int out_size, void* d_ws, size_t ws_size,
                              hipStream_t stream) {
    const float* Q = (const float*)d_in[0];
    const float* Kin = (const float*)d_in[1];
    const float* V = (const float*)d_in[2];
    const float* Wq = (const float*)d_in[3];
    const float* Wk = (const float*)d_in[4];
    const float* Wv = (const float*)d_in[5];
    const float* dw = (const float*)d_in[6];
    const float* pw = (const float*)d_in[7];
    const float* sep_bias = (const float*)d_in[8];
    const float* Wck = (const float*)d_in[9];
    const float* bck = (const float*)d_in[10];
    const float* Wco = (const float*)d_in[11];
    const float* bco = (const float*)d_in[12];
    const float* gammas = (const float*)d_in[13];
    const int* mask = (const int*)d_in[14];
    float* out = (float*)d_out;
    float* ws = (float*)d_ws;

    const size_t NP = (size_t)MROWS * ALLH;        // 3145728
    const size_t WSZ = (size_t)ALLH * HID;         // 294912
    float* qb   = ws;                              // f32 q (spankern)
    float* cob  = qb + NP;
    float* kcb  = cob + NP;
    float* kern = kcb + NP;                        // 8192*54
    ushort* qh  = (ushort*)(kern + (size_t)MROWS * HEADS * KS);
    ushort* khm = qh + NP;                         // swizzled K tiles
    ushort* vhm = khm + NP;                        // transposed+swizzled V tiles
    ushort* ybf = vhm + NP;                        // dconv out bf16 [8192][768]
    ushort* WqT = ybf + (size_t)MROWS * HID;
    ushort* WkT = WqT + WSZ;
    ushort* WvT = WkT + WSZ;
    ushort* WcoT = WvT + WSZ;
    ushort* pwT = WcoT + WSZ;

    // 1. depthwise conv (register sliding window) + weight conversions
    dconv_kernel<<<dim3(3, 16, BATCH), 256, 0, stream>>>(Kin, dw, ybf);
    wcvt_kernel<<<dim3(24, 12, 4), 256, 0, stream>>>(Wq, Wk, Wv, Wco, WqT, WkT, WvT, WcoT);
    pwcvt_kernel<<<(ALLH * HID + 255) / 256, 256, 0, stream>>>(pw, pwT);

    // 2. all five projection GEMMs, one 128x128-tile dispatch, 8 waves/block
    gemm_all<<<960, 512, 0, stream>>>(Q, Kin, V, ybf, WqT, WkT, WvT, WcoT, pwT,
                                      bco, sep_bias, qb, qh, khm, vhm, cob, kcb);

    // 3. span-dynamic-conv kernel weights + softmax
    spankern_kernel<<<MROWS / 4, 256, 0, stream>>>(kcb, qb, Wck, bck, kern);

    // 4. conv branch output (channels 384..767), register sliding window
    convout_kernel<<<dim3(3, 16, BATCH), 256, 0, stream>>>(cob, kern, out);

    // 5. fused monotonic attention (channels 0..383)
    attn_mfma<<<BATCH * HEADS * (SEQ / 64), 256, 0, stream>>>(qh, khm, vhm, mask, gammas, out);
}